// Round 3
// baseline (244.857 us; speedup 1.0000x reference)
//
#include <hip/hip_runtime.h>

// Problem constants: B=4, S=2048, D=1024
#define BB 4
#define SS 2048
#define DD 1024
#define MM 8192               // total rows
#define CH 64                 // scan chunks per batch
#define RR 32                 // rows per chunk (CH*RR = SS)
#define PI_F 3.14159265358979323846f

typedef __attribute__((ext_vector_type(8))) short bf16x8;
typedef __attribute__((ext_vector_type(4))) float f32x4;

// ---------------------------------------------------------------------------
// fp32 <-> bf16 helpers (RNE)
// ---------------------------------------------------------------------------
__device__ __forceinline__ unsigned short f2bf(float f) {
  unsigned int u = __float_as_uint(f);
  u = (u + 0x7FFFu + ((u >> 16) & 1u)) >> 16;
  return (unsigned short)u;
}
__device__ __forceinline__ float bf2f(unsigned short h) {
  return __uint_as_float(((unsigned int)h) << 16);
}

__global__ __launch_bounds__(256) void convert_bf16(
    const float* __restrict__ src, unsigned short* __restrict__ dst) {
  const long i = ((long)blockIdx.x * 256 + threadIdx.x) * 4;
  const float4 v = *(const float4*)&src[i];
  ushort4 o;
  o.x = f2bf(v.x); o.y = f2bf(v.y); o.z = f2bf(v.z); o.w = f2bf(v.w);
  *(ushort4*)&dst[i] = o;
}

__global__ __launch_bounds__(256) void convert_w(
    const float* __restrict__ Wq, const float* __restrict__ Wk,
    const float* __restrict__ Wv, unsigned short* __restrict__ dst) {
  const int z = blockIdx.y;
  const float* src = (z == 0) ? Wq : (z == 1) ? Wk : Wv;
  const long i = ((long)blockIdx.x * 256 + threadIdx.x) * 4;
  const float4 v = *(const float4*)&src[i];
  ushort4 o;
  o.x = f2bf(v.x); o.y = f2bf(v.y); o.z = f2bf(v.z); o.w = f2bf(v.w);
  *(ushort4*)&dst[(size_t)z * DD * DD + i] = o;
}

// ---------------------------------------------------------------------------
// MFMA GEMM — 256x256 tile, BK=64, 8 waves (2M x 4N, 128x64 out/wave),
// deep-pipelined with counted vmcnt (never drains in main loop).
// [R1 structure — best measured 75.6us. R2's 8-barrier variant regressed.]
// ---------------------------------------------------------------------------
__device__ __forceinline__ void async16(const void* g, void* l) {
  __builtin_amdgcn_global_load_lds(
      (const __attribute__((address_space(1))) void*)g,
      (__attribute__((address_space(3))) void*)l, 16, 0, 0);
}

#define GW(n)  asm volatile("s_waitcnt vmcnt(" #n ")" ::: "memory")
#define LW()   do { asm volatile("s_waitcnt lgkmcnt(0)" ::: "memory"); \
                    __builtin_amdgcn_sched_barrier(0); } while (0)
#define BAR()  asm volatile("s_barrier" ::: "memory")

#define STA(buf, i, T) async16(xb + (size_t)(m0 + 64 * (i)) * DD + (T) * 64 + aOff, \
                               &Als[(buf) * 16384 + (i) * 4096 + slot8])
#define STB(buf, p, T) async16(W + (size_t)(n0 + 16 * (p)) * DD + (T) * 64 + bOff, \
                               &Bls[(buf) * 16384 + (p) * 4096 + slot8])
#define LDA(buf) { _Pragma("unroll") for (int mt = 0; mt < 8; ++mt) { \
    af[mt][0] = *(const bf16x8*)&Als[(buf) * 16384 + aRd + mt * 1024 + qoff0]; \
    af[mt][1] = *(const bf16x8*)&Als[(buf) * 16384 + aRd + mt * 1024 + qoff1]; } }
#define LDB(buf, p) { \
    bfv[0] = *(const bf16x8*)&Bls[(buf) * 16384 + (p) * 4096 + bRd + qoff0]; \
    bfv[1] = *(const bf16x8*)&Bls[(buf) * 16384 + (p) * 4096 + bRd + qoff1]; }
#define MMA(p) { __builtin_amdgcn_s_setprio(1); \
    _Pragma("unroll") for (int mt = 0; mt < 8; ++mt) { \
      acc[mt][p] = __builtin_amdgcn_mfma_f32_16x16x32_bf16(af[mt][0], bfv[0], acc[mt][p], 0, 0, 0); \
      acc[mt][p] = __builtin_amdgcn_mfma_f32_16x16x32_bf16(af[mt][1], bfv[1], acc[mt][p], 0, 0, 0); } \
    __builtin_amdgcn_s_setprio(0); }

__global__ __launch_bounds__(512, 2) void gemm_mfma(
    const unsigned short* __restrict__ xb,
    const unsigned short* __restrict__ Wb,
    float* __restrict__ outq, unsigned short* __restrict__ KV) {
  const int z = blockIdx.z;
  const unsigned short* W = Wb + (size_t)z * DD * DD;

  __shared__ unsigned short Als[2 * 16384];   // 64 KB
  __shared__ unsigned short Bls[2 * 16384];   // 64 KB

  const int tid  = threadIdx.x;
  const int lane = tid & 63;
  const int w    = tid >> 6;          // wave 0..7
  const int wm   = w >> 2;            // M half (0..1)
  const int gq   = w & 3;             // N quarter group (0..3)
  const int fr   = lane & 15;
  const int kq   = lane >> 4;

  const int m0 = blockIdx.x * 256;
  const int n0 = blockIdx.y * 256;

  // staging geometry: unit = 8 KB = 512 threads x 16 B; slot -> (row, quad)
  const int slot  = tid;
  const int srow  = slot >> 3;                 // row within 64-row unit
  const int sq    = (slot & 7) ^ (srow & 7);   // swizzled source quad
  const int slot8 = slot * 8;                  // shorts (lane-linear dest)
  const size_t aOff = (size_t)srow * DD + sq * 8;
  const size_t bOff = (size_t)(64 * (slot >> 7) + ((slot >> 3) & 15)) * DD + sq * 8;

  // read-side addressing (same XOR as stage-source swizzle)
  const int qoff0 = ((0 + kq) ^ (fr & 7)) * 8;
  const int qoff1 = ((4 + kq) ^ (fr & 7)) * 8;
  const int aRd = wm * 8192 + fr * 64;
  const int bRd = gq * 1024 + fr * 64;

  f32x4 acc[8][4] = {};
  bf16x8 af[8][2];
  bf16x8 bfv[2];

  // Prologue: 14 units, order matches steady-state stream for T=0,1.
  STA(0, 0, 0); STA(0, 1, 0);
  STA(0, 2, 0); STB(0, 0, 0);
  STA(0, 3, 0); STB(0, 1, 0);
  STB(0, 2, 0); STB(0, 3, 0);
  STA(1, 0, 1); STA(1, 1, 1);
  STA(1, 2, 1); STB(1, 0, 1);
  STA(1, 3, 1); STB(1, 1, 1);

  // Main loop: tiles 0..13 (NT=16), steady waits (9,10,11,12).
  for (int T = 0; T < 14; ++T) {
    const int buf = T & 1;
    GW(9);  BAR(); LDA(buf); LDB(buf, 0);
    STB(buf ^ 1, 2, T + 1); STB(buf ^ 1, 3, T + 1); LW(); MMA(0);
    GW(10); BAR(); LDB(buf, 1);
    STA(buf, 0, T + 2); STA(buf, 1, T + 2);         LW(); MMA(1);
    GW(11); BAR(); LDB(buf, 2);
    STA(buf, 2, T + 2); STB(buf, 0, T + 2);         LW(); MMA(2);
    GW(12); BAR(); LDB(buf, 3);
    STA(buf, 3, T + 2); STB(buf, 1, T + 2);         LW(); MMA(3);
  }
  // T = 14 (buf 0): stage only B(15) r2,r3; waits adjust for skipped stages.
  GW(9);  BAR(); LDA(0); LDB(0, 0); STB(1, 2, 15); STB(1, 3, 15); LW(); MMA(0);
  GW(10); BAR(); LDB(0, 1); LW(); MMA(1); BAR();
  GW(9);  BAR(); LDB(0, 2); LW(); MMA(2);
  GW(8);  BAR(); LDB(0, 3); LW(); MMA(3);
  // T = 15 (buf 1): no stages; drain.
  GW(3);  BAR(); LDA(1); LDB(1, 0); LW(); MMA(0);
  GW(2);  BAR(); LDB(1, 1); LW(); MMA(1);
  GW(1);  BAR(); LDB(1, 2); LW(); MMA(2);
  GW(0);  BAR(); LDB(1, 3); LW(); MMA(3);

  // Epilogue
  const int col = lane & 15;
  const int r0  = (lane >> 4) * 4;
  const int mBase = m0 + wm * 128;
  const int nBase = n0 + gq * 64;
  if (z == 0) {
    #pragma unroll
    for (int mt = 0; mt < 8; ++mt)
      #pragma unroll
      for (int p = 0; p < 4; ++p)
        #pragma unroll
        for (int r = 0; r < 4; ++r)
          outq[(size_t)(mBase + mt * 16 + r0 + r) * DD + nBase + p * 16 + col] =
              acc[mt][p][r];
  } else {
    unsigned short* Ck = KV + (size_t)(z - 1) * DD;
    #pragma unroll
    for (int mt = 0; mt < 8; ++mt)
      #pragma unroll
      for (int p = 0; p < 4; ++p)
        #pragma unroll
        for (int r = 0; r < 4; ++r)
          Ck[(size_t)(mBase + mt * 16 + r0 + r) * 2048 + nBase + p * 16 + col] =
              f2bf(acc[mt][p][r]);
  }
}

// ---------------------------------------------------------------------------
// Radix-4 FFT, N=1024, 256 threads, 4 complex/thread in registers (R5/R6
// known-good). Forward DIF -> base-4 digit-reversed order; inverse DIT back.
// Twiddles from a per-block LDS table (w1,w2,w3 per stage): one sincos per
// thread at init replaces 4 (bind) / 8 (unbind) sincos+complex-square chains
// per FFT. Same formulas, sign factored -> numerically identical.
// ---------------------------------------------------------------------------
__device__ __forceinline__ int pidx(int i) { return i + (i >> 6); }
#define BUFSZ 1040
__device__ __forceinline__ int pidx16(int i) { return i + (i >> 4); }
#define MEMSZ 546   // 513 slots + pads
#define TWSZ 1020   // 3*(256+64+16+4) float2

__device__ __forceinline__ int rev4(int p) {
  unsigned r = __brev((unsigned)p) >> 22;
  return (int)(((r & 0x155u) << 1) | ((r & 0x2AAu) >> 1));
}

__host__ __device__ constexpr int clog2(int s) {
  return (s == 256) ? 8 : (s == 64) ? 6 : (s == 16) ? 4 : (s == 4) ? 2 : 0;
}
__host__ __device__ constexpr int twoff(int s) {
  return (s == 256) ? 0 : (s == 64) ? 768 : (s == 16) ? 960 : 1008;
}

__device__ __forceinline__ void tw_section(float2* tw, int base, int j, float denom) {
  float s, c;
  __sincosf(2.0f * PI_F * (float)j / denom, &s, &c);
  const float c2 = c * c - s * s, s2 = 2.0f * c * s;
  tw[base + j] = make_float2(c, s);
  tw[base + (int)(denom * 0.25f) + j] = make_float2(c2, s2);
  tw[base + (int)(denom * 0.5f) + j] = make_float2(c * c2 - s * s2, c * s2 + s * c2);
}

__device__ __forceinline__ void tw_init(float2* tw, int t) {
  tw_section(tw, 0, t, 1024.0f);
  if (t < 64) tw_section(tw, 768, t, 256.0f);
  if (t < 16) tw_section(tw, 960, t, 64.0f);
  if (t < 4)  tw_section(tw, 1008, t, 16.0f);
}

template <int S>
__device__ __forceinline__ void fwd_stage(float2 x[4], int t, const float2* tw) {
  float c1 = 1.0f, s1 = 0.0f, c2 = 1.0f, s2 = 0.0f, c3 = 1.0f, s3 = 0.0f;
  if (S > 1) {
    const int j = t & (S - 1);
    const float2* b = tw + twoff(S);
    const float2 w1 = b[j], w2 = b[S + j], w3 = b[2 * S + j];
    c1 = w1.x; s1 = -w1.y; c2 = w2.x; s2 = -w2.y; c3 = w3.x; s3 = -w3.y;
  }
  const float Ar = x[0].x + x[2].x, Ai = x[0].y + x[2].y;
  const float Br = x[1].x + x[3].x, Bi = x[1].y + x[3].y;
  const float Cr = x[0].x - x[2].x, Ci = x[0].y - x[2].y;
  const float dr = x[1].x - x[3].x, di = x[1].y - x[3].y;
  const float y1r = Cr + di, y1i = Ci - dr;
  const float y2r = Ar - Br, y2i = Ai - Bi;
  const float y3r = Cr - di, y3i = Ci + dr;
  x[0] = make_float2(Ar + Br, Ai + Bi);
  x[1] = make_float2(y1r * c1 - y1i * s1, y1r * s1 + y1i * c1);
  x[2] = make_float2(y2r * c2 - y2i * s2, y2r * s2 + y2i * c2);
  x[3] = make_float2(y3r * c3 - y3i * s3, y3r * s3 + y3i * c3);
}

template <int S>
__device__ __forceinline__ void inv_stage(float2 x[4], int t, const float2* tw) {
  float c1 = 1.0f, s1 = 0.0f, c2 = 1.0f, s2 = 0.0f, c3 = 1.0f, s3 = 0.0f;
  if (S > 1) {
    const int j = t & (S - 1);
    const float2* b = tw + twoff(S);
    const float2 w1 = b[j], w2 = b[S + j], w3 = b[2 * S + j];
    c1 = w1.x; s1 = w1.y; c2 = w2.x; s2 = w2.y; c3 = w3.x; s3 = w3.y;
  }
  const float u0r = x[0].x,                   u0i = x[0].y;
  const float u1r = x[1].x * c1 - x[1].y * s1, u1i = x[1].x * s1 + x[1].y * c1;
  const float u2r = x[2].x * c2 - x[2].y * s2, u2i = x[2].x * s2 + x[2].y * c2;
  const float u3r = x[3].x * c3 - x[3].y * s3, u3i = x[3].x * s3 + x[3].y * c3;
  const float Er = u0r + u2r, Ei = u0i + u2i;
  const float Fr = u0r - u2r, Fi = u0i - u2i;
  const float Gr = u1r + u3r, Gi = u1i + u3i;
  const float Hr = u1r - u3r, Hi = u1i - u3i;
  x[0] = make_float2(Er + Gr, Ei + Gi);
  x[1] = make_float2(Fr - Hi, Fi + Hr);
  x[2] = make_float2(Er - Gr, Ei - Gi);
  x[3] = make_float2(Fr + Hi, Fi - Hr);
}

template <int SW, int SR>
__device__ __forceinline__ void xchg(float2* buf, float2 x[4], int t) {
  constexpr int LW2 = clog2(SW), LR = clog2(SR);
  #pragma unroll
  for (int n = 0; n < 4; ++n)
    buf[pidx(((t >> LW2) << (LW2 + 2)) + (t & (SW - 1)) + n * SW)] = x[n];
  __syncthreads();
  #pragma unroll
  for (int n = 0; n < 4; ++n)
    x[n] = buf[pidx(((t >> LR) << (LR + 2)) + (t & (SR - 1)) + n * SR)];
  __syncthreads();
}

__device__ __forceinline__ void fwd_fft(float2* buf, float2 x[4], int t,
                                        const float2* tw) {
  fwd_stage<256>(x, t, tw); xchg<256, 64>(buf, x, t);
  fwd_stage<64>(x, t, tw);  xchg<64, 16>(buf, x, t);
  fwd_stage<16>(x, t, tw);  xchg<16, 4>(buf, x, t);
  fwd_stage<4>(x, t, tw);   xchg<4, 1>(buf, x, t);
  fwd_stage<1>(x, t, tw);
  #pragma unroll
  for (int n = 0; n < 4; ++n) buf[pidx(4 * t + n)] = x[n];
  __syncthreads();
}

// ---------------------------------------------------------------------------
// Bind (in place): KV row [k|v] bf16 (4 KB) -> one FFT of k+iv, Hermitian
// split, P = fk*fv packed to HALF spectrum over the same 4 KB:
//   slot 0 = (P[0], P[512]) (both exactly real), slot s = P[s], s=1..511.
// ---------------------------------------------------------------------------
__global__ __launch_bounds__(256) void bind_kernel(unsigned short* __restrict__ KV) {
  __shared__ float2 buf[BUFSZ];
  __shared__ float2 tws[TWSZ];
  const int t = threadIdx.x;
  unsigned short* row = KV + (long)blockIdx.x * 2048;

  tw_init(tws, t);

  float2 x[4];
  #pragma unroll
  for (int n = 0; n < 4; ++n) {
    const int i = t + 256 * n;
    x[n] = make_float2(bf2f(row[i]), bf2f(row[1024 + i]));   // k + i*v
  }
  __syncthreads();                       // tw table ready
  fwd_fft(buf, x, t, tws);

  float2* Prow = (float2*)row;
  #pragma unroll
  for (int m = 0; m < 2; ++m) {
    const int s = t + 256 * m;
    if (s == 0) {
      const float2 W0   = buf[pidx(0)];
      const float2 W512 = buf[pidx(2)];
      Prow[0] = make_float2(W0.x * W0.y, W512.x * W512.y);
    } else {
      const int p1 = rev4(s);
      const int p2 = rev4(1024 - s);
      const float2 F1 = buf[pidx(p1)], F2 = buf[pidx(p2)];
      const float fkr = 0.5f * (F1.x + F2.x), fki = 0.5f * (F1.y - F2.y);
      const float fvr = 0.5f * (F1.y + F2.y), fvi = 0.5f * (F2.x - F1.x);
      Prow[s] = make_float2(fkr * fvr - fki * fvi, fkr * fvi + fki * fvr);
    }
  }
}

// ---------------------------------------------------------------------------
// Causal cumsum over s per packed bin; grids cover nB batches (gridDim.y=2*nB).
// ---------------------------------------------------------------------------
__global__ __launch_bounds__(256) void scan_chunk_sum(
    const float2* __restrict__ P, float2* __restrict__ csum) {
  const int chunk = blockIdx.x;
  const int batch = blockIdx.y >> 1;
  const int f = (blockIdx.y & 1) * 256 + threadIdx.x;
  long base = ((long)batch * SS + (long)chunk * RR) * 512 + f;
  float sr = 0.0f, si = 0.0f;
  #pragma unroll
  for (int i0 = 0; i0 < RR; i0 += 8) {
    float2 p[8];
    #pragma unroll
    for (int j = 0; j < 8; ++j) p[j] = P[base + (long)(i0 + j) * 512];
    #pragma unroll
    for (int j = 0; j < 8; ++j) { sr += p[j].x; si += p[j].y; }
  }
  csum[((long)batch * CH + chunk) * 512 + f] = make_float2(sr, si);
}

__global__ __launch_bounds__(256) void scan_chunk_scan(float2* csum) {
  const int idx = blockIdx.x * 256 + threadIdx.x;
  const int batch = idx >> 9;
  const int f = idx & 511;
  float2 v[CH];
  #pragma unroll
  for (int c = 0; c < CH; ++c) v[c] = csum[((long)batch * CH + c) * 512 + f];
  float rr = 0.0f, ri = 0.0f;
  #pragma unroll
  for (int c = 0; c < CH; ++c) {
    const float2 x = v[c];
    csum[((long)batch * CH + c) * 512 + f] = make_float2(rr, ri);
    rr += x.x; ri += x.y;
  }
}

__global__ __launch_bounds__(256) void scan_apply(
    float2* __restrict__ P, const float2* __restrict__ csum) {
  const int chunk = blockIdx.x;
  const int batch = blockIdx.y >> 1;
  const int f = (blockIdx.y & 1) * 256 + threadIdx.x;
  float2 off = csum[((long)batch * CH + chunk) * 512 + f];
  float ar = off.x, ai = off.y;
  long base = ((long)batch * SS + (long)chunk * RR) * 512 + f;
  #pragma unroll
  for (int i0 = 0; i0 < RR; i0 += 8) {
    float2 p[8];
    #pragma unroll
    for (int j = 0; j < 8; ++j) p[j] = P[base + (long)(i0 + j) * 512];
    #pragma unroll
    for (int j = 0; j < 8; ++j) {
      ar += p[j].x; ai += p[j].y;
      P[base + (long)(i0 + j) * 512] = make_float2(ar, ai);
    }
  }
}

// ---------------------------------------------------------------------------
// Unbind, 2 rows/block (in place on d_out). mem rows Hermitian-packed;
// unpack into LDS, gather with predicated conj; one fwd FFT (q0+iq1),
// one inv FFT (z0+iz1).
// ---------------------------------------------------------------------------
__global__ __launch_bounds__(256) void unbind_kernel(
    float* __restrict__ qout, const float2* __restrict__ mem) {
  __shared__ float2 buf[BUFSZ];
  __shared__ float2 m0s[MEMSZ], m1s[MEMSZ];
  __shared__ float2 tws[TWSZ];
  const int t = threadIdx.x;
  const long r0 = (long)blockIdx.x * 2;
  float* row0 = qout + r0 * DD;
  float* row1 = row0 + DD;
  const float2* mem0 = mem + r0 * 512;
  const float2* mem1 = mem0 + 512;

  tw_init(tws, t);

  float2 x[4];
  #pragma unroll
  for (int n = 0; n < 4; ++n) {
    const int i = t + 256 * n;
    x[n] = make_float2(row0[i], row1[i]);        // q0 + i*q1
  }
  #pragma unroll
  for (int n = 0; n < 2; ++n) {
    const int s = t + 256 * n;
    const float2 a = mem0[s], b = mem1[s];
    if (s == 0) {
      m0s[pidx16(0)]   = make_float2(a.x, 0.0f);
      m0s[pidx16(512)] = make_float2(a.y, 0.0f);
      m1s[pidx16(0)]   = make_float2(b.x, 0.0f);
      m1s[pidx16(512)] = make_float2(b.y, 0.0f);
    } else {
      m0s[pidx16(s)] = a;
      m1s[pidx16(s)] = b;
    }
  }
  __syncthreads();                       // tw table ready (m*s ordered too)
  fwd_fft(buf, x, t, tws);

  float2 z[4];
  #pragma unroll
  for (int m = 0; m < 4; ++m) {
    const int p   = t + 256 * m;
    const int bin = rev4(p);
    const int p2  = rev4((1024 - bin) & 1023);
    const float2 F1 = buf[pidx(p)], F2 = buf[pidx(p2)];
    const float q0r = 0.5f * (F1.x + F2.x), q0i = 0.5f * (F1.y - F2.y);
    const float q1r = 0.5f * (F1.y + F2.y), q1i = 0.5f * (F2.x - F1.x);
    const int  ix = (bin <= 512) ? bin : 1024 - bin;
    const float sg = (bin <= 512) ? 1.0f : -1.0f;
    float2 m0 = m0s[pidx16(ix)], m1 = m1s[pidx16(ix)];
    m0.y *= sg; m1.y *= sg;
    const float z0r = m0.x * q0r + m0.y * q0i, z0i = m0.y * q0r - m0.x * q0i;
    const float z1r = m1.x * q1r + m1.y * q1i, z1i = m1.y * q1r - m1.x * q1i;
    z[m] = make_float2(z0r - z1i, z0i + z1r);    // z0 + i*z1
  }
  __syncthreads();
  #pragma unroll
  for (int m = 0; m < 4; ++m) buf[pidx(t + 256 * m)] = z[m];
  __syncthreads();
  #pragma unroll
  for (int n = 0; n < 4; ++n) x[n] = buf[pidx(4 * t + n)];

  inv_stage<1>(x, t, tws);   xchg<1, 4>(buf, x, t);
  inv_stage<4>(x, t, tws);   xchg<4, 16>(buf, x, t);
  inv_stage<16>(x, t, tws);  xchg<16, 64>(buf, x, t);
  inv_stage<64>(x, t, tws);  xchg<64, 256>(buf, x, t);
  inv_stage<256>(x, t, tws);

  const float sc = 1.0f / 1024.0f;
  #pragma unroll
  for (int n = 0; n < 4; ++n) {
    const int i = t + 256 * n;
    row0[i] = x[n].x * sc;
    row1[i] = x[n].y * sc;
  }
}

// ---------------------------------------------------------------------------
extern "C" void kernel_launch(void* const* d_in, const int* in_sizes, int n_in,
                              void* d_out, int out_size, void* d_ws, size_t ws_size,
                              hipStream_t stream) {
  (void)in_sizes; (void)n_in; (void)out_size;
  const float* x  = (const float*)d_in[0];
  const float* Wq = (const float*)d_in[1];
  const float* Wk = (const float*)d_in[2];
  const float* Wv = (const float*)d_in[3];
  float* out = (float*)d_out;

  // ws layout for MH rows/pass, nB batches/pass:
  //   Wb   : 3*1024*1024 bf16       = 6.29 MB
  //   xb   : MH*1024 bf16
  //   KV/P : MH rows * 4 KB
  //   csum : nB*64*512 float2
  // Single-pass (MH=8192): 57.67 MB; two-pass (MH=4096): 32.0 MB. Branch on
  // ws_size — constant across calls, so graph-safe.
  const size_t wbytes = (size_t)3 * DD * DD * 2;
  auto need = [&](size_t MHr, size_t nB) {
    return wbytes + MHr * DD * 2 + MHr * 4096 + nB * CH * 512 * 8;
  };
  const int nPass = (ws_size >= need(8192, 4)) ? 1 : 2;
  const size_t MH = MM / nPass;          // rows per pass
  const int    nB = BB / nPass;          // batches per pass

  char* ws = (char*)d_ws;
  unsigned short* Wb = (unsigned short*)ws;
  unsigned short* xb = (unsigned short*)(ws + wbytes);
  unsigned short* KV = (unsigned short*)(ws + wbytes + MH * DD * 2);
  float2*       csum = (float2*)((char*)KV + MH * 4096);

  convert_w<<<dim3(DD * DD / 1024, 3), 256, 0, stream>>>(Wq, Wk, Wv, Wb);

  for (int h = 0; h < nPass; ++h) {
    const float* xh   = x   + (size_t)h * MH * DD;
    float*       outh = out + (size_t)h * MH * DD;

    convert_bf16<<<MH * DD / 1024, 256, 0, stream>>>(xh, xb);
    gemm_mfma<<<dim3(MH / 256, DD / 256, 3), dim3(512), 0, stream>>>(xb, Wb, outh, KV);
    bind_kernel<<<MH, 256, 0, stream>>>(KV);
    scan_chunk_sum<<<dim3(CH, nB * 2), 256, 0, stream>>>((const float2*)KV, csum);
    scan_chunk_scan<<<nB * 2, 256, 0, stream>>>(csum);
    scan_apply<<<dim3(CH, nB * 2), 256, 0, stream>>>((float2*)KV, csum);
    unbind_kernel<<<MH / 2, 256, 0, stream>>>(outh, (const float2*)KV);
  }
}

// Round 4
// 233.492 us; speedup vs baseline: 1.0487x; 1.0487x over previous
//
#include <hip/hip_runtime.h>

// Problem constants: B=4, S=2048, D=1024
#define BB 4
#define SS 2048
#define DD 1024
#define MM 8192               // total rows
#define CH 64                 // scan chunks per batch
#define RR 32                 // rows per chunk (CH*RR = SS)
#define PI_F 3.14159265358979323846f

typedef __attribute__((ext_vector_type(8))) short bf16x8;
typedef __attribute__((ext_vector_type(4))) float f32x4;

// ---------------------------------------------------------------------------
// fp32 <-> bf16 helpers (RNE)
// ---------------------------------------------------------------------------
__device__ __forceinline__ unsigned short f2bf(float f) {
  unsigned int u = __float_as_uint(f);
  u = (u + 0x7FFFu + ((u >> 16) & 1u)) >> 16;
  return (unsigned short)u;
}
__device__ __forceinline__ float bf2f(unsigned short h) {
  return __uint_as_float(((unsigned int)h) << 16);
}

__global__ __launch_bounds__(256) void convert_bf16(
    const float* __restrict__ src, unsigned short* __restrict__ dst) {
  const long i = ((long)blockIdx.x * 256 + threadIdx.x) * 4;
  const float4 v = *(const float4*)&src[i];
  ushort4 o;
  o.x = f2bf(v.x); o.y = f2bf(v.y); o.z = f2bf(v.z); o.w = f2bf(v.w);
  *(ushort4*)&dst[i] = o;
}

__global__ __launch_bounds__(256) void convert_w(
    const float* __restrict__ Wq, const float* __restrict__ Wk,
    const float* __restrict__ Wv, unsigned short* __restrict__ dst) {
  const int z = blockIdx.y;
  const float* src = (z == 0) ? Wq : (z == 1) ? Wk : Wv;
  const long i = ((long)blockIdx.x * 256 + threadIdx.x) * 4;
  const float4 v = *(const float4*)&src[i];
  ushort4 o;
  o.x = f2bf(v.x); o.y = f2bf(v.y); o.z = f2bf(v.z); o.w = f2bf(v.w);
  *(ushort4*)&dst[(size_t)z * DD * DD + i] = o;
}

// ---------------------------------------------------------------------------
// MFMA GEMM — 256x256 tile, BK=64, 8 waves (2M x 4N, 128x64 out/wave).
// R1 stage/barrier skeleton, now with PIPELINED LDS READS:
//  - no forced lgkmcnt(0): compiler inserts precise counted waits per frag
//  - B frags double-banked (bva/bvb); phase p+1's reads issue before phase
//    p's MFMAs, so only a 2-read dependency is exposed per phase after P0
//  - single derived vmcnt(6) at tile start covers ALL of tile T (queue:
//    B(T)p3 has exactly 6 younger stage-loads at P0(T), T=0..14; 0 at T=15)
//  - sched_barrier(0) before each s_barrier pins MFMAs (and their implicit
//    lgkmcnt) before the barrier -> region-reuse safety (rule #18)
// Region safety (stage targets vs last reader, all verified):
//  P1 STA u0,u1 over A(T): af read at P0, waited before MMA0 < P1-BAR
//  P2 STA u2 / STB p0 over A(T),B(T)p0: read at P0/P1 phase, < P2-BAR
//  P3 STA u3 / STB p1: read < P3-BAR;  P0 STB p2,p3 (other buf): read in T-1
// z=0: q fp32 -> outq. z=1,2: k,v bf16 -> KV interleaved [row][k|v], ld 2048.
// ---------------------------------------------------------------------------
__device__ __forceinline__ void async16(const void* g, void* l) {
  __builtin_amdgcn_global_load_lds(
      (const __attribute__((address_space(1))) void*)g,
      (__attribute__((address_space(3))) void*)l, 16, 0, 0);
}

#define GW(n)  asm volatile("s_waitcnt vmcnt(" #n ")" ::: "memory")
#define BAR()  asm volatile("s_barrier" ::: "memory")
#define SB0()  __builtin_amdgcn_sched_barrier(0)

#define STA(buf, i, T) async16(xb + (size_t)(m0 + 64 * (i)) * DD + (T) * 64 + aOff, \
                               &Als[(buf) * 16384 + (i) * 4096 + slot8])
#define STB(buf, p, T) async16(W + (size_t)(n0 + 16 * (p)) * DD + (T) * 64 + bOff, \
                               &Bls[(buf) * 16384 + (p) * 4096 + slot8])
#define LDA(buf) { _Pragma("unroll") for (int mt = 0; mt < 8; ++mt) { \
    af[mt][0] = *(const bf16x8*)&Als[(buf) * 16384 + aRd + mt * 1024 + qoff0]; \
    af[mt][1] = *(const bf16x8*)&Als[(buf) * 16384 + aRd + mt * 1024 + qoff1]; } }
#define LDB(buf, p, bank) { \
    bank[0] = *(const bf16x8*)&Bls[(buf) * 16384 + (p) * 4096 + bRd + qoff0]; \
    bank[1] = *(const bf16x8*)&Bls[(buf) * 16384 + (p) * 4096 + bRd + qoff1]; }
#define MMA(p, bank) { __builtin_amdgcn_s_setprio(1); \
    _Pragma("unroll") for (int mt = 0; mt < 8; ++mt) { \
      acc[mt][p] = __builtin_amdgcn_mfma_f32_16x16x32_bf16(af[mt][0], bank[0], acc[mt][p], 0, 0, 0); \
      acc[mt][p] = __builtin_amdgcn_mfma_f32_16x16x32_bf16(af[mt][1], bank[1], acc[mt][p], 0, 0, 0); } \
    __builtin_amdgcn_s_setprio(0); }

__global__ __launch_bounds__(512, 2) void gemm_mfma(
    const unsigned short* __restrict__ xb,
    const unsigned short* __restrict__ Wb,
    float* __restrict__ outq, unsigned short* __restrict__ KV) {
  const int z = blockIdx.z;
  const unsigned short* W = Wb + (size_t)z * DD * DD;

  __shared__ unsigned short Als[2 * 16384];   // 64 KB
  __shared__ unsigned short Bls[2 * 16384];   // 64 KB

  const int tid  = threadIdx.x;
  const int lane = tid & 63;
  const int w    = tid >> 6;          // wave 0..7
  const int wm   = w >> 2;            // M half (0..1)
  const int gq   = w & 3;             // N quarter group (0..3)
  const int fr   = lane & 15;
  const int kq   = lane >> 4;

  const int m0 = blockIdx.x * 256;
  const int n0 = blockIdx.y * 256;

  // staging geometry: unit = 8 KB = 512 threads x 16 B; slot -> (row, quad)
  const int slot  = tid;
  const int srow  = slot >> 3;                 // row within 64-row unit
  const int sq    = (slot & 7) ^ (srow & 7);   // swizzled source quad
  const int slot8 = slot * 8;                  // shorts (lane-linear dest)
  const size_t aOff = (size_t)srow * DD + sq * 8;
  const size_t bOff = (size_t)(64 * (slot >> 7) + ((slot >> 3) & 15)) * DD + sq * 8;

  // read-side addressing (same XOR as stage-source swizzle)
  const int qoff0 = ((0 + kq) ^ (fr & 7)) * 8;
  const int qoff1 = ((4 + kq) ^ (fr & 7)) * 8;
  const int aRd = wm * 8192 + fr * 64;
  const int bRd = gq * 1024 + fr * 64;

  f32x4 acc[8][4] = {};
  bf16x8 af[8][2];
  bf16x8 bva[2], bvb[2];

  // Prologue: 14 units, order matches steady-state stream for T=0,1.
  STA(0, 0, 0); STA(0, 1, 0);
  STA(0, 2, 0); STB(0, 0, 0);
  STA(0, 3, 0); STB(0, 1, 0);
  STB(0, 2, 0); STB(0, 3, 0);
  STA(1, 0, 1); STA(1, 1, 1);
  STA(1, 2, 1); STB(1, 0, 1);
  STA(1, 3, 1); STB(1, 1, 1);

  // Main loop: tiles 0..13 (NT=16); uniform vmcnt(6) covers all of tile T.
  for (int T = 0; T < 14; ++T) {
    const int buf = T & 1;
    SB0(); GW(6); BAR();
    LDA(buf); LDB(buf, 0, bva);
    STB(buf ^ 1, 2, T + 1); STB(buf ^ 1, 3, T + 1);
    LDB(buf, 1, bvb);
    MMA(0, bva);
    SB0(); BAR();
    STA(buf, 0, T + 2); STA(buf, 1, T + 2);
    LDB(buf, 2, bva);
    MMA(1, bvb);
    SB0(); BAR();
    STA(buf, 2, T + 2); STB(buf, 0, T + 2);
    LDB(buf, 3, bvb);
    MMA(2, bva);
    SB0(); BAR();
    STA(buf, 3, T + 2); STB(buf, 1, T + 2);
    MMA(3, bvb);
  }
  // T = 14 (buf 0): only remaining stage is B(15)p2,p3 at P0.
  SB0(); GW(6); BAR();
  LDA(0); LDB(0, 0, bva);
  STB(1, 2, 15); STB(1, 3, 15);
  LDB(0, 1, bvb);
  MMA(0, bva);
  SB0(); BAR(); LDB(0, 2, bva); MMA(1, bvb);
  SB0(); BAR(); LDB(0, 3, bvb); MMA(2, bva);
  SB0(); BAR(); MMA(3, bvb);
  // T = 15 (buf 1): drain all.
  SB0(); GW(0); BAR();
  LDA(1); LDB(1, 0, bva); LDB(1, 1, bvb);
  MMA(0, bva);
  SB0(); BAR(); LDB(1, 2, bva); MMA(1, bvb);
  SB0(); BAR(); LDB(1, 3, bvb); MMA(2, bva);
  SB0(); BAR(); MMA(3, bvb);

  // Epilogue
  const int col = lane & 15;
  const int r0  = (lane >> 4) * 4;
  const int mBase = m0 + wm * 128;
  const int nBase = n0 + gq * 64;
  if (z == 0) {
    #pragma unroll
    for (int mt = 0; mt < 8; ++mt)
      #pragma unroll
      for (int p = 0; p < 4; ++p)
        #pragma unroll
        for (int r = 0; r < 4; ++r)
          outq[(size_t)(mBase + mt * 16 + r0 + r) * DD + nBase + p * 16 + col] =
              acc[mt][p][r];
  } else {
    unsigned short* Ck = KV + (size_t)(z - 1) * DD;
    #pragma unroll
    for (int mt = 0; mt < 8; ++mt)
      #pragma unroll
      for (int p = 0; p < 4; ++p)
        #pragma unroll
        for (int r = 0; r < 4; ++r)
          Ck[(size_t)(mBase + mt * 16 + r0 + r) * 2048 + nBase + p * 16 + col] =
              f2bf(acc[mt][p][r]);
  }
}

// ---------------------------------------------------------------------------
// Radix-4 FFT, N=1024, 256 threads, 4 complex/thread in registers (proven
// sincos version — LDS twiddle tables regressed via occupancy, reverted).
// Forward DIF -> base-4 digit-reversed order; inverse DIT back.
// ---------------------------------------------------------------------------
__device__ __forceinline__ int pidx(int i) { return i + (i >> 6); }
#define BUFSZ 1040
__device__ __forceinline__ int pidx16(int i) { return i + (i >> 4); }
#define MEMSZ 546   // 513 slots + pads

__device__ __forceinline__ int rev4(int p) {
  unsigned r = __brev((unsigned)p) >> 22;
  return (int)(((r & 0x155u) << 1) | ((r & 0x2AAu) >> 1));
}

__host__ __device__ constexpr int clog2(int s) {
  return (s == 256) ? 8 : (s == 64) ? 6 : (s == 16) ? 4 : (s == 4) ? 2 : 0;
}

template <int S>
__device__ __forceinline__ void fwd_stage(float2 x[4], int t) {
  float c1 = 1.0f, s1 = 0.0f;
  if (S > 1) {
    const int j = t & (S - 1);
    __sincosf(-2.0f * PI_F * (float)j / (float)(4 * S), &s1, &c1);
  }
  const float c2 = c1 * c1 - s1 * s1, s2 = 2.0f * c1 * s1;
  const float c3 = c1 * c2 - s1 * s2, s3 = c1 * s2 + s1 * c2;
  const float Ar = x[0].x + x[2].x, Ai = x[0].y + x[2].y;
  const float Br = x[1].x + x[3].x, Bi = x[1].y + x[3].y;
  const float Cr = x[0].x - x[2].x, Ci = x[0].y - x[2].y;
  const float dr = x[1].x - x[3].x, di = x[1].y - x[3].y;
  const float y1r = Cr + di, y1i = Ci - dr;
  const float y2r = Ar - Br, y2i = Ai - Bi;
  const float y3r = Cr - di, y3i = Ci + dr;
  x[0] = make_float2(Ar + Br, Ai + Bi);
  x[1] = make_float2(y1r * c1 - y1i * s1, y1r * s1 + y1i * c1);
  x[2] = make_float2(y2r * c2 - y2i * s2, y2r * s2 + y2i * c2);
  x[3] = make_float2(y3r * c3 - y3i * s3, y3r * s3 + y3i * c3);
}

template <int S>
__device__ __forceinline__ void inv_stage(float2 x[4], int t) {
  float c1 = 1.0f, s1 = 0.0f;
  if (S > 1) {
    const int j = t & (S - 1);
    __sincosf(2.0f * PI_F * (float)j / (float)(4 * S), &s1, &c1);
  }
  const float c2 = c1 * c1 - s1 * s1, s2 = 2.0f * c1 * s1;
  const float c3 = c1 * c2 - s1 * s2, s3 = c1 * s2 + s1 * c2;
  const float u0r = x[0].x,                   u0i = x[0].y;
  const float u1r = x[1].x * c1 - x[1].y * s1, u1i = x[1].x * s1 + x[1].y * c1;
  const float u2r = x[2].x * c2 - x[2].y * s2, u2i = x[2].x * s2 + x[2].y * c2;
  const float u3r = x[3].x * c3 - x[3].y * s3, u3i = x[3].x * s3 + x[3].y * c3;
  const float Er = u0r + u2r, Ei = u0i + u2i;
  const float Fr = u0r - u2r, Fi = u0i - u2i;
  const float Gr = u1r + u3r, Gi = u1i + u3i;
  const float Hr = u1r - u3r, Hi = u1i - u3i;
  x[0] = make_float2(Er + Gr, Ei + Gi);
  x[1] = make_float2(Fr - Hi, Fi + Hr);
  x[2] = make_float2(Er - Gr, Ei - Gi);
  x[3] = make_float2(Fr + Hi, Fi - Hr);
}

template <int SW, int SR>
__device__ __forceinline__ void xchg(float2* buf, float2 x[4], int t) {
  constexpr int LW2 = clog2(SW), LR = clog2(SR);
  #pragma unroll
  for (int n = 0; n < 4; ++n)
    buf[pidx(((t >> LW2) << (LW2 + 2)) + (t & (SW - 1)) + n * SW)] = x[n];
  __syncthreads();
  #pragma unroll
  for (int n = 0; n < 4; ++n)
    x[n] = buf[pidx(((t >> LR) << (LR + 2)) + (t & (SR - 1)) + n * SR)];
  __syncthreads();
}

__device__ __forceinline__ void fwd_fft(float2* buf, float2 x[4], int t) {
  fwd_stage<256>(x, t); xchg<256, 64>(buf, x, t);
  fwd_stage<64>(x, t);  xchg<64, 16>(buf, x, t);
  fwd_stage<16>(x, t);  xchg<16, 4>(buf, x, t);
  fwd_stage<4>(x, t);   xchg<4, 1>(buf, x, t);
  fwd_stage<1>(x, t);
  #pragma unroll
  for (int n = 0; n < 4; ++n) buf[pidx(4 * t + n)] = x[n];
  __syncthreads();
}

// ---------------------------------------------------------------------------
// Bind (in place): KV row [k|v] bf16 (4 KB) -> one FFT of k+iv, Hermitian
// split, P = fk*fv packed to HALF spectrum over the same 4 KB:
//   slot 0 = (P[0], P[512]) (both exactly real), slot s = P[s], s=1..511.
// ---------------------------------------------------------------------------
__global__ __launch_bounds__(256) void bind_kernel(unsigned short* __restrict__ KV) {
  __shared__ float2 buf[BUFSZ];
  const int t = threadIdx.x;
  unsigned short* row = KV + (long)blockIdx.x * 2048;

  float2 x[4];
  #pragma unroll
  for (int n = 0; n < 4; ++n) {
    const int i = t + 256 * n;
    x[n] = make_float2(bf2f(row[i]), bf2f(row[1024 + i]));   // k + i*v
  }
  fwd_fft(buf, x, t);

  float2* Prow = (float2*)row;
  #pragma unroll
  for (int m = 0; m < 2; ++m) {
    const int s = t + 256 * m;
    if (s == 0) {
      const float2 W0   = buf[pidx(0)];
      const float2 W512 = buf[pidx(2)];
      Prow[0] = make_float2(W0.x * W0.y, W512.x * W512.y);
    } else {
      const int p1 = rev4(s);
      const int p2 = rev4(1024 - s);
      const float2 F1 = buf[pidx(p1)], F2 = buf[pidx(p2)];
      const float fkr = 0.5f * (F1.x + F2.x), fki = 0.5f * (F1.y - F2.y);
      const float fvr = 0.5f * (F1.y + F2.y), fvi = 0.5f * (F2.x - F1.x);
      Prow[s] = make_float2(fkr * fvr - fki * fvi, fkr * fvi + fki * fvr);
    }
  }
}

// ---------------------------------------------------------------------------
// Causal cumsum over s per packed bin; grids cover nB batches (gridDim.y=2*nB).
// Loads batched 8-deep (breaks dependent-latency chain); order preserved.
// ---------------------------------------------------------------------------
__global__ __launch_bounds__(256) void scan_chunk_sum(
    const float2* __restrict__ P, float2* __restrict__ csum) {
  const int chunk = blockIdx.x;
  const int batch = blockIdx.y >> 1;
  const int f = (blockIdx.y & 1) * 256 + threadIdx.x;
  long base = ((long)batch * SS + (long)chunk * RR) * 512 + f;
  float sr = 0.0f, si = 0.0f;
  #pragma unroll
  for (int i0 = 0; i0 < RR; i0 += 8) {
    float2 p[8];
    #pragma unroll
    for (int j = 0; j < 8; ++j) p[j] = P[base + (long)(i0 + j) * 512];
    #pragma unroll
    for (int j = 0; j < 8; ++j) { sr += p[j].x; si += p[j].y; }
  }
  csum[((long)batch * CH + chunk) * 512 + f] = make_float2(sr, si);
}

__global__ __launch_bounds__(256) void scan_chunk_scan(float2* csum) {
  const int idx = blockIdx.x * 256 + threadIdx.x;
  const int batch = idx >> 9;
  const int f = idx & 511;
  float2 v[CH];
  #pragma unroll
  for (int c = 0; c < CH; ++c) v[c] = csum[((long)batch * CH + c) * 512 + f];
  float rr = 0.0f, ri = 0.0f;
  #pragma unroll
  for (int c = 0; c < CH; ++c) {
    const float2 x = v[c];
    csum[((long)batch * CH + c) * 512 + f] = make_float2(rr, ri);
    rr += x.x; ri += x.y;
  }
}

__global__ __launch_bounds__(256) void scan_apply(
    float2* __restrict__ P, const float2* __restrict__ csum) {
  const int chunk = blockIdx.x;
  const int batch = blockIdx.y >> 1;
  const int f = (blockIdx.y & 1) * 256 + threadIdx.x;
  float2 off = csum[((long)batch * CH + chunk) * 512 + f];
  float ar = off.x, ai = off.y;
  long base = ((long)batch * SS + (long)chunk * RR) * 512 + f;
  #pragma unroll
  for (int i0 = 0; i0 < RR; i0 += 8) {
    float2 p[8];
    #pragma unroll
    for (int j = 0; j < 8; ++j) p[j] = P[base + (long)(i0 + j) * 512];
    #pragma unroll
    for (int j = 0; j < 8; ++j) {
      ar += p[j].x; ai += p[j].y;
      P[base + (long)(i0 + j) * 512] = make_float2(ar, ai);
    }
  }
}

// ---------------------------------------------------------------------------
// Unbind, 2 rows/block (in place on d_out). mem rows Hermitian-packed;
// unpack into LDS, gather with predicated conj; one fwd FFT (q0+iq1),
// one inv FFT (z0+iz1).
// ---------------------------------------------------------------------------
__global__ __launch_bounds__(256) void unbind_kernel(
    float* __restrict__ qout, const float2* __restrict__ mem) {
  __shared__ float2 buf[BUFSZ];
  __shared__ float2 m0s[MEMSZ], m1s[MEMSZ];
  const int t = threadIdx.x;
  const long r0 = (long)blockIdx.x * 2;
  float* row0 = qout + r0 * DD;
  float* row1 = row0 + DD;
  const float2* mem0 = mem + r0 * 512;
  const float2* mem1 = mem0 + 512;

  float2 x[4];
  #pragma unroll
  for (int n = 0; n < 4; ++n) {
    const int i = t + 256 * n;
    x[n] = make_float2(row0[i], row1[i]);        // q0 + i*q1
  }
  #pragma unroll
  for (int n = 0; n < 2; ++n) {
    const int s = t + 256 * n;
    const float2 a = mem0[s], b = mem1[s];
    if (s == 0) {
      m0s[pidx16(0)]   = make_float2(a.x, 0.0f);
      m0s[pidx16(512)] = make_float2(a.y, 0.0f);
      m1s[pidx16(0)]   = make_float2(b.x, 0.0f);
      m1s[pidx16(512)] = make_float2(b.y, 0.0f);
    } else {
      m0s[pidx16(s)] = a;
      m1s[pidx16(s)] = b;
    }
  }
  fwd_fft(buf, x, t);   // internal barriers order the m*s writes too

  float2 z[4];
  #pragma unroll
  for (int m = 0; m < 4; ++m) {
    const int p   = t + 256 * m;
    const int bin = rev4(p);
    const int p2  = rev4((1024 - bin) & 1023);
    const float2 F1 = buf[pidx(p)], F2 = buf[pidx(p2)];
    const float q0r = 0.5f * (F1.x + F2.x), q0i = 0.5f * (F1.y - F2.y);
    const float q1r = 0.5f * (F1.y + F2.y), q1i = 0.5f * (F2.x - F1.x);
    const int  ix = (bin <= 512) ? bin : 1024 - bin;
    const float sg = (bin <= 512) ? 1.0f : -1.0f;
    float2 m0 = m0s[pidx16(ix)], m1 = m1s[pidx16(ix)];
    m0.y *= sg; m1.y *= sg;
    const float z0r = m0.x * q0r + m0.y * q0i, z0i = m0.y * q0r - m0.x * q0i;
    const float z1r = m1.x * q1r + m1.y * q1i, z1i = m1.y * q1r - m1.x * q1i;
    z[m] = make_float2(z0r - z1i, z0i + z1r);    // z0 + i*z1
  }
  __syncthreads();
  #pragma unroll
  for (int m = 0; m < 4; ++m) buf[pidx(t + 256 * m)] = z[m];
  __syncthreads();
  #pragma unroll
  for (int n = 0; n < 4; ++n) x[n] = buf[pidx(4 * t + n)];

  inv_stage<1>(x, t);   xchg<1, 4>(buf, x, t);
  inv_stage<4>(x, t);   xchg<4, 16>(buf, x, t);
  inv_stage<16>(x, t);  xchg<16, 64>(buf, x, t);
  inv_stage<64>(x, t);  xchg<64, 256>(buf, x, t);
  inv_stage<256>(x, t);

  const float sc = 1.0f / 1024.0f;
  #pragma unroll
  for (int n = 0; n < 4; ++n) {
    const int i = t + 256 * n;
    row0[i] = x[n].x * sc;
    row1[i] = x[n].y * sc;
  }
}

// ---------------------------------------------------------------------------
extern "C" void kernel_launch(void* const* d_in, const int* in_sizes, int n_in,
                              void* d_out, int out_size, void* d_ws, size_t ws_size,
                              hipStream_t stream) {
  (void)in_sizes; (void)n_in; (void)out_size;
  const float* x  = (const float*)d_in[0];
  const float* Wq = (const float*)d_in[1];
  const float* Wk = (const float*)d_in[2];
  const float* Wv = (const float*)d_in[3];
  float* out = (float*)d_out;

  // ws layout for MH rows/pass, nB batches/pass:
  //   Wb   : 3*1024*1024 bf16       = 6.29 MB
  //   xb   : MH*1024 bf16
  //   KV/P : MH rows * 4 KB
  //   csum : nB*64*512 float2
  // Single-pass (MH=8192): 57.67 MB; two-pass (MH=4096): 32.0 MB. Branch on
  // ws_size — constant across calls, so graph-safe.
  const size_t wbytes = (size_t)3 * DD * DD * 2;
  auto need = [&](size_t MHr, size_t nB) {
    return wbytes + MHr * DD * 2 + MHr * 4096 + nB * CH * 512 * 8;
  };
  const int nPass = (ws_size >= need(8192, 4)) ? 1 : 2;
  const size_t MH = MM / nPass;          // rows per pass
  const int    nB = BB / nPass;          // batches per pass

  char* ws = (char*)d_ws;
  unsigned short* Wb = (unsigned short*)ws;
  unsigned short* xb = (unsigned short*)(ws + wbytes);
  unsigned short* KV = (unsigned short*)(ws + wbytes + MH * DD * 2);
  float2*       csum = (float2*)((char*)KV + MH * 4096);

  convert_w<<<dim3(DD * DD / 1024, 3), 256, 0, stream>>>(Wq, Wk, Wv, Wb);

  for (int h = 0; h < nPass; ++h) {
    const float* xh   = x   + (size_t)h * MH * DD;
    float*       outh = out + (size_t)h * MH * DD;

    convert_bf16<<<MH * DD / 1024, 256, 0, stream>>>(xh, xb);
    gemm_mfma<<<dim3(MH / 256, DD / 256, 3), dim3(512), 0, stream>>>(xb, Wb, outh, KV);
    bind_kernel<<<MH, 256, 0, stream>>>(KV);
    scan_chunk_sum<<<dim3(CH, nB * 2), 256, 0, stream>>>((const float2*)KV, csum);
    scan_chunk_scan<<<nB * 2, 256, 0, stream>>>(csum);
    scan_apply<<<dim3(CH, nB * 2), 256, 0, stream>>>((float2*)KV, csum);
    unbind_kernel<<<MH / 2, 256, 0, stream>>>(outh, (const float2*)KV);
  }
}

// Round 5
// 228.675 us; speedup vs baseline: 1.0708x; 1.0211x over previous
//
#include <hip/hip_runtime.h>

// Problem constants: B=4, S=2048, D=1024
#define BB 4
#define SS 2048
#define DD 1024
#define MM 8192               // total rows
#define CH 64                 // scan chunks per batch
#define RR 32                 // rows per chunk (CH*RR = SS)
#define PI_F 3.14159265358979323846f

typedef __attribute__((ext_vector_type(8))) short bf16x8;
typedef __attribute__((ext_vector_type(4))) float f32x4;

// ---------------------------------------------------------------------------
// fp32 <-> bf16 helpers (RNE)
// ---------------------------------------------------------------------------
__device__ __forceinline__ unsigned short f2bf(float f) {
  unsigned int u = __float_as_uint(f);
  u = (u + 0x7FFFu + ((u >> 16) & 1u)) >> 16;
  return (unsigned short)u;
}
__device__ __forceinline__ float bf2f(unsigned short h) {
  return __uint_as_float(((unsigned int)h) << 16);
}

__global__ __launch_bounds__(256) void convert_bf16(
    const float* __restrict__ src, unsigned short* __restrict__ dst) {
  const long i = ((long)blockIdx.x * 256 + threadIdx.x) * 4;
  const float4 v = *(const float4*)&src[i];
  ushort4 o;
  o.x = f2bf(v.x); o.y = f2bf(v.y); o.z = f2bf(v.z); o.w = f2bf(v.w);
  *(ushort4*)&dst[i] = o;
}

__global__ __launch_bounds__(256) void convert_w(
    const float* __restrict__ Wq, const float* __restrict__ Wk,
    const float* __restrict__ Wv, unsigned short* __restrict__ dst) {
  const int z = blockIdx.y;
  const float* src = (z == 0) ? Wq : (z == 1) ? Wk : Wv;
  const long i = ((long)blockIdx.x * 256 + threadIdx.x) * 4;
  const float4 v = *(const float4*)&src[i];
  ushort4 o;
  o.x = f2bf(v.x); o.y = f2bf(v.y); o.z = f2bf(v.z); o.w = f2bf(v.w);
  *(ushort4*)&dst[(size_t)z * DD * DD + i] = o;
}

// ---------------------------------------------------------------------------
// MFMA GEMM — 256x256 tile, BK=64, 8 waves (2M x 4N, 128x64 out/wave).
// TWO phases per K-tile (was 4): 32 MFMA per barrier region, halving the
// measured ~250-300cy/barrier lockstep cost (R2 vs R4 isolated it).
//   Ph0(T): reads A(T) all (16) + B(T)p0,p1 (4); stages B(T+1)p2,p3 +
//           A(T+1)u2,u3; MMA(0),MMA(1).
//   Ph1(T): reads B(T)p2,p3 (4); stages A(T+2)u0,u1 + B(T+2)p0,p1;
//           MMA(2),MMA(3).
// vmcnt(4) once per tile at Ph0 (outstanding there = Ph1(T-1)'s 4 stages;
// everything tile T needs is older). GW(0) at final tile.
// Region-reuse safety (stage target vs last reader, all >=1 barrier apart,
// reads lgkm-retired pre-barrier since their MMAs precede the barrier):
//   Ph0(T) STA A(T+1)u2,u3 [buf^1]: last read Ph0(T-1) (2 barriers)
//   Ph0(T) STB B(T+1)p2,p3 [buf^1]: last read Ph1(T-1) (1 barrier)
//   Ph1(T) STA A(T+2)u0,u1 [buf]  : last read Ph0(T)   (1 barrier)
//   Ph1(T) STB B(T+2)p0,p1 [buf]  : last read Ph0(T)   (1 barrier)
// MFMA accumulation order identical to R4 -> bit-identical output.
// z=0: q fp32 -> outq. z=1,2: k,v bf16 -> KV interleaved [row][k|v], ld 2048.
// ---------------------------------------------------------------------------
__device__ __forceinline__ void async16(const void* g, void* l) {
  __builtin_amdgcn_global_load_lds(
      (const __attribute__((address_space(1))) void*)g,
      (__attribute__((address_space(3))) void*)l, 16, 0, 0);
}

#define GW(n)  asm volatile("s_waitcnt vmcnt(" #n ")" ::: "memory")
#define BAR()  asm volatile("s_barrier" ::: "memory")
#define SB0()  __builtin_amdgcn_sched_barrier(0)

#define STA(buf, i, T) async16(xb + (size_t)(m0 + 64 * (i)) * DD + (T) * 64 + aOff, \
                               &Als[(buf) * 16384 + (i) * 4096 + slot8])
#define STB(buf, p, T) async16(W + (size_t)(n0 + 16 * (p)) * DD + (T) * 64 + bOff, \
                               &Bls[(buf) * 16384 + (p) * 4096 + slot8])
#define LDA(buf) { _Pragma("unroll") for (int mt = 0; mt < 8; ++mt) { \
    af[mt][0] = *(const bf16x8*)&Als[(buf) * 16384 + aRd + mt * 1024 + qoff0]; \
    af[mt][1] = *(const bf16x8*)&Als[(buf) * 16384 + aRd + mt * 1024 + qoff1]; } }
#define LDB(buf, p, bank) { \
    bank[0] = *(const bf16x8*)&Bls[(buf) * 16384 + (p) * 4096 + bRd + qoff0]; \
    bank[1] = *(const bf16x8*)&Bls[(buf) * 16384 + (p) * 4096 + bRd + qoff1]; }
#define MMA(p, bank) { __builtin_amdgcn_s_setprio(1); \
    _Pragma("unroll") for (int mt = 0; mt < 8; ++mt) { \
      acc[mt][p] = __builtin_amdgcn_mfma_f32_16x16x32_bf16(af[mt][0], bank[0], acc[mt][p], 0, 0, 0); \
      acc[mt][p] = __builtin_amdgcn_mfma_f32_16x16x32_bf16(af[mt][1], bank[1], acc[mt][p], 0, 0, 0); } \
    __builtin_amdgcn_s_setprio(0); }

__global__ __launch_bounds__(512, 2) void gemm_mfma(
    const unsigned short* __restrict__ xb,
    const unsigned short* __restrict__ Wb,
    float* __restrict__ outq, unsigned short* __restrict__ KV) {
  const int z = blockIdx.z;
  const unsigned short* W = Wb + (size_t)z * DD * DD;

  __shared__ unsigned short Als[2 * 16384];   // 64 KB
  __shared__ unsigned short Bls[2 * 16384];   // 64 KB

  const int tid  = threadIdx.x;
  const int lane = tid & 63;
  const int w    = tid >> 6;          // wave 0..7
  const int wm   = w >> 2;            // M half (0..1)
  const int gq   = w & 3;             // N quarter group (0..3)
  const int fr   = lane & 15;
  const int kq   = lane >> 4;

  const int m0 = blockIdx.x * 256;
  const int n0 = blockIdx.y * 256;

  // staging geometry: unit = 8 KB = 512 threads x 16 B; slot -> (row, quad)
  const int slot  = tid;
  const int srow  = slot >> 3;                 // row within 64-row unit
  const int sq    = (slot & 7) ^ (srow & 7);   // swizzled source quad
  const int slot8 = slot * 8;                  // shorts (lane-linear dest)
  const size_t aOff = (size_t)srow * DD + sq * 8;
  const size_t bOff = (size_t)(64 * (slot >> 7) + ((slot >> 3) & 15)) * DD + sq * 8;

  // read-side addressing (same XOR as stage-source swizzle)
  const int qoff0 = ((0 + kq) ^ (fr & 7)) * 8;
  const int qoff1 = ((4 + kq) ^ (fr & 7)) * 8;
  const int aRd = wm * 8192 + fr * 64;
  const int bRd = gq * 1024 + fr * 64;

  f32x4 acc[8][4] = {};
  bf16x8 af[8][2];
  bf16x8 bva[2], bvb[2];

  // Prologue: 12 units — tile0 full (8), then the "Ph1(-1)" set for tile1.
  STA(0, 0, 0); STA(0, 1, 0); STA(0, 2, 0); STA(0, 3, 0);
  STB(0, 0, 0); STB(0, 1, 0); STB(0, 2, 0); STB(0, 3, 0);
  STA(1, 0, 1); STA(1, 1, 1); STB(1, 0, 1); STB(1, 1, 1);

  // Main loop: tiles 0..13 (NT=16), 2 phases/tile, vmcnt(4) once per tile.
  for (int T = 0; T < 14; ++T) {
    const int buf = T & 1;
    // Ph0
    SB0(); GW(4); BAR();
    LDB(buf, 0, bva);
    LDA(buf);
    LDB(buf, 1, bvb);
    STB(buf ^ 1, 2, T + 1); STB(buf ^ 1, 3, T + 1);
    STA(buf ^ 1, 2, T + 1); STA(buf ^ 1, 3, T + 1);
    MMA(0, bva);
    MMA(1, bvb);
    // Ph1
    SB0(); BAR();
    LDB(buf, 2, bva);
    LDB(buf, 3, bvb);
    STA(buf, 0, T + 2); STA(buf, 1, T + 2);
    STB(buf, 0, T + 2); STB(buf, 1, T + 2);
    MMA(2, bva);
    MMA(3, bvb);
  }
  // T = 14 (buf 0): Ph0 stages tile-15 remainder; Ph1 stages nothing.
  SB0(); GW(4); BAR();
  LDB(0, 0, bva); LDA(0); LDB(0, 1, bvb);
  STB(1, 2, 15); STB(1, 3, 15); STA(1, 2, 15); STA(1, 3, 15);
  MMA(0, bva); MMA(1, bvb);
  SB0(); BAR();
  LDB(0, 2, bva); LDB(0, 3, bvb);
  MMA(2, bva); MMA(3, bvb);
  // T = 15 (buf 1): drain all outstanding stages, no new stages.
  SB0(); GW(0); BAR();
  LDB(1, 0, bva); LDA(1); LDB(1, 1, bvb);
  MMA(0, bva); MMA(1, bvb);
  SB0(); BAR();
  LDB(1, 2, bva); LDB(1, 3, bvb);
  MMA(2, bva); MMA(3, bvb);

  // Epilogue
  const int col = lane & 15;
  const int r0  = (lane >> 4) * 4;
  const int mBase = m0 + wm * 128;
  const int nBase = n0 + gq * 64;
  if (z == 0) {
    #pragma unroll
    for (int mt = 0; mt < 8; ++mt)
      #pragma unroll
      for (int p = 0; p < 4; ++p)
        #pragma unroll
        for (int r = 0; r < 4; ++r)
          outq[(size_t)(mBase + mt * 16 + r0 + r) * DD + nBase + p * 16 + col] =
              acc[mt][p][r];
  } else {
    unsigned short* Ck = KV + (size_t)(z - 1) * DD;
    #pragma unroll
    for (int mt = 0; mt < 8; ++mt)
      #pragma unroll
      for (int p = 0; p < 4; ++p)
        #pragma unroll
        for (int r = 0; r < 4; ++r)
          Ck[(size_t)(mBase + mt * 16 + r0 + r) * 2048 + nBase + p * 16 + col] =
              f2bf(acc[mt][p][r]);
  }
}

// ---------------------------------------------------------------------------
// Radix-4 FFT, N=1024, 256 threads, 4 complex/thread in registers (proven
// sincos version). Forward DIF -> base-4 digit-reversed order; inverse DIT.
// ---------------------------------------------------------------------------
__device__ __forceinline__ int pidx(int i) { return i + (i >> 6); }
#define BUFSZ 1040
__device__ __forceinline__ int pidx16(int i) { return i + (i >> 4); }
#define MEMSZ 546   // 513 slots + pads

__device__ __forceinline__ int rev4(int p) {
  unsigned r = __brev((unsigned)p) >> 22;
  return (int)(((r & 0x155u) << 1) | ((r & 0x2AAu) >> 1));
}

__host__ __device__ constexpr int clog2(int s) {
  return (s == 256) ? 8 : (s == 64) ? 6 : (s == 16) ? 4 : (s == 4) ? 2 : 0;
}

template <int S>
__device__ __forceinline__ void fwd_stage(float2 x[4], int t) {
  float c1 = 1.0f, s1 = 0.0f;
  if (S > 1) {
    const int j = t & (S - 1);
    __sincosf(-2.0f * PI_F * (float)j / (float)(4 * S), &s1, &c1);
  }
  const float c2 = c1 * c1 - s1 * s1, s2 = 2.0f * c1 * s1;
  const float c3 = c1 * c2 - s1 * s2, s3 = c1 * s2 + s1 * c2;
  const float Ar = x[0].x + x[2].x, Ai = x[0].y + x[2].y;
  const float Br = x[1].x + x[3].x, Bi = x[1].y + x[3].y;
  const float Cr = x[0].x - x[2].x, Ci = x[0].y - x[2].y;
  const float dr = x[1].x - x[3].x, di = x[1].y - x[3].y;
  const float y1r = Cr + di, y1i = Ci - dr;
  const float y2r = Ar - Br, y2i = Ai - Bi;
  const float y3r = Cr - di, y3i = Ci + dr;
  x[0] = make_float2(Ar + Br, Ai + Bi);
  x[1] = make_float2(y1r * c1 - y1i * s1, y1r * s1 + y1i * c1);
  x[2] = make_float2(y2r * c2 - y2i * s2, y2r * s2 + y2i * c2);
  x[3] = make_float2(y3r * c3 - y3i * s3, y3r * s3 + y3i * c3);
}

template <int S>
__device__ __forceinline__ void inv_stage(float2 x[4], int t) {
  float c1 = 1.0f, s1 = 0.0f;
  if (S > 1) {
    const int j = t & (S - 1);
    __sincosf(2.0f * PI_F * (float)j / (float)(4 * S), &s1, &c1);
  }
  const float c2 = c1 * c1 - s1 * s1, s2 = 2.0f * c1 * s1;
  const float c3 = c1 * c2 - s1 * s2, s3 = c1 * s2 + s1 * c2;
  const float u0r = x[0].x,                   u0i = x[0].y;
  const float u1r = x[1].x * c1 - x[1].y * s1, u1i = x[1].x * s1 + x[1].y * c1;
  const float u2r = x[2].x * c2 - x[2].y * s2, u2i = x[2].x * s2 + x[2].y * c2;
  const float u3r = x[3].x * c3 - x[3].y * s3, u3i = x[3].x * s3 + x[3].y * c3;
  const float Er = u0r + u2r, Ei = u0i + u2i;
  const float Fr = u0r - u2r, Fi = u0i - u2i;
  const float Gr = u1r + u3r, Gi = u1i + u3i;
  const float Hr = u1r - u3r, Hi = u1i - u3i;
  x[0] = make_float2(Er + Gr, Ei + Gi);
  x[1] = make_float2(Fr - Hi, Fi + Hr);
  x[2] = make_float2(Er - Gr, Ei - Gi);
  x[3] = make_float2(Fr + Hi, Fi - Hr);
}

template <int SW, int SR>
__device__ __forceinline__ void xchg(float2* buf, float2 x[4], int t) {
  constexpr int LW2 = clog2(SW), LR = clog2(SR);
  #pragma unroll
  for (int n = 0; n < 4; ++n)
    buf[pidx(((t >> LW2) << (LW2 + 2)) + (t & (SW - 1)) + n * SW)] = x[n];
  __syncthreads();
  #pragma unroll
  for (int n = 0; n < 4; ++n)
    x[n] = buf[pidx(((t >> LR) << (LR + 2)) + (t & (SR - 1)) + n * SR)];
  __syncthreads();
}

__device__ __forceinline__ void fwd_fft(float2* buf, float2 x[4], int t) {
  fwd_stage<256>(x, t); xchg<256, 64>(buf, x, t);
  fwd_stage<64>(x, t);  xchg<64, 16>(buf, x, t);
  fwd_stage<16>(x, t);  xchg<16, 4>(buf, x, t);
  fwd_stage<4>(x, t);   xchg<4, 1>(buf, x, t);
  fwd_stage<1>(x, t);
  #pragma unroll
  for (int n = 0; n < 4; ++n) buf[pidx(4 * t + n)] = x[n];
  __syncthreads();
}

// ---------------------------------------------------------------------------
// Bind (in place): KV row [k|v] bf16 (4 KB) -> one FFT of k+iv, Hermitian
// split, P = fk*fv packed to HALF spectrum over the same 4 KB:
//   slot 0 = (P[0], P[512]) (both exactly real), slot s = P[s], s=1..511.
// ---------------------------------------------------------------------------
__global__ __launch_bounds__(256) void bind_kernel(unsigned short* __restrict__ KV) {
  __shared__ float2 buf[BUFSZ];
  const int t = threadIdx.x;
  unsigned short* row = KV + (long)blockIdx.x * 2048;

  float2 x[4];
  #pragma unroll
  for (int n = 0; n < 4; ++n) {
    const int i = t + 256 * n;
    x[n] = make_float2(bf2f(row[i]), bf2f(row[1024 + i]));   // k + i*v
  }
  fwd_fft(buf, x, t);

  float2* Prow = (float2*)row;
  #pragma unroll
  for (int m = 0; m < 2; ++m) {
    const int s = t + 256 * m;
    if (s == 0) {
      const float2 W0   = buf[pidx(0)];
      const float2 W512 = buf[pidx(2)];
      Prow[0] = make_float2(W0.x * W0.y, W512.x * W512.y);
    } else {
      const int p1 = rev4(s);
      const int p2 = rev4(1024 - s);
      const float2 F1 = buf[pidx(p1)], F2 = buf[pidx(p2)];
      const float fkr = 0.5f * (F1.x + F2.x), fki = 0.5f * (F1.y - F2.y);
      const float fvr = 0.5f * (F1.y + F2.y), fvi = 0.5f * (F2.x - F1.x);
      Prow[s] = make_float2(fkr * fvr - fki * fvi, fkr * fvi + fki * fvr);
    }
  }
}

// ---------------------------------------------------------------------------
// Causal cumsum over s per packed bin; grids cover nB batches (gridDim.y=2*nB).
// Loads batched 8-deep (breaks dependent-latency chain); order preserved.
// ---------------------------------------------------------------------------
__global__ __launch_bounds__(256) void scan_chunk_sum(
    const float2* __restrict__ P, float2* __restrict__ csum) {
  const int chunk = blockIdx.x;
  const int batch = blockIdx.y >> 1;
  const int f = (blockIdx.y & 1) * 256 + threadIdx.x;
  long base = ((long)batch * SS + (long)chunk * RR) * 512 + f;
  float sr = 0.0f, si = 0.0f;
  #pragma unroll
  for (int i0 = 0; i0 < RR; i0 += 8) {
    float2 p[8];
    #pragma unroll
    for (int j = 0; j < 8; ++j) p[j] = P[base + (long)(i0 + j) * 512];
    #pragma unroll
    for (int j = 0; j < 8; ++j) { sr += p[j].x; si += p[j].y; }
  }
  csum[((long)batch * CH + chunk) * 512 + f] = make_float2(sr, si);
}

__global__ __launch_bounds__(256) void scan_chunk_scan(float2* csum) {
  const int idx = blockIdx.x * 256 + threadIdx.x;
  const int batch = idx >> 9;
  const int f = idx & 511;
  float2 v[CH];
  #pragma unroll
  for (int c = 0; c < CH; ++c) v[c] = csum[((long)batch * CH + c) * 512 + f];
  float rr = 0.0f, ri = 0.0f;
  #pragma unroll
  for (int c = 0; c < CH; ++c) {
    const float2 x = v[c];
    csum[((long)batch * CH + c) * 512 + f] = make_float2(rr, ri);
    rr += x.x; ri += x.y;
  }
}

__global__ __launch_bounds__(256) void scan_apply(
    float2* __restrict__ P, const float2* __restrict__ csum) {
  const int chunk = blockIdx.x;
  const int batch = blockIdx.y >> 1;
  const int f = (blockIdx.y & 1) * 256 + threadIdx.x;
  float2 off = csum[((long)batch * CH + chunk) * 512 + f];
  float ar = off.x, ai = off.y;
  long base = ((long)batch * SS + (long)chunk * RR) * 512 + f;
  #pragma unroll
  for (int i0 = 0; i0 < RR; i0 += 8) {
    float2 p[8];
    #pragma unroll
    for (int j = 0; j < 8; ++j) p[j] = P[base + (long)(i0 + j) * 512];
    #pragma unroll
    for (int j = 0; j < 8; ++j) {
      ar += p[j].x; ai += p[j].y;
      P[base + (long)(i0 + j) * 512] = make_float2(ar, ai);
    }
  }
}

// ---------------------------------------------------------------------------
// Unbind, 2 rows/block (in place on d_out). mem rows Hermitian-packed;
// unpack into LDS, gather with predicated conj; one fwd FFT (q0+iq1),
// one inv FFT (z0+iz1).
// ---------------------------------------------------------------------------
__global__ __launch_bounds__(256) void unbind_kernel(
    float* __restrict__ qout, const float2* __restrict__ mem) {
  __shared__ float2 buf[BUFSZ];
  __shared__ float2 m0s[MEMSZ], m1s[MEMSZ];
  const int t = threadIdx.x;
  const long r0 = (long)blockIdx.x * 2;
  float* row0 = qout + r0 * DD;
  float* row1 = row0 + DD;
  const float2* mem0 = mem + r0 * 512;
  const float2* mem1 = mem0 + 512;

  float2 x[4];
  #pragma unroll
  for (int n = 0; n < 4; ++n) {
    const int i = t + 256 * n;
    x[n] = make_float2(row0[i], row1[i]);        // q0 + i*q1
  }
  #pragma unroll
  for (int n = 0; n < 2; ++n) {
    const int s = t + 256 * n;
    const float2 a = mem0[s], b = mem1[s];
    if (s == 0) {
      m0s[pidx16(0)]   = make_float2(a.x, 0.0f);
      m0s[pidx16(512)] = make_float2(a.y, 0.0f);
      m1s[pidx16(0)]   = make_float2(b.x, 0.0f);
      m1s[pidx16(512)] = make_float2(b.y, 0.0f);
    } else {
      m0s[pidx16(s)] = a;
      m1s[pidx16(s)] = b;
    }
  }
  fwd_fft(buf, x, t);   // internal barriers order the m*s writes too

  float2 z[4];
  #pragma unroll
  for (int m = 0; m < 4; ++m) {
    const int p   = t + 256 * m;
    const int bin = rev4(p);
    const int p2  = rev4((1024 - bin) & 1023);
    const float2 F1 = buf[pidx(p)], F2 = buf[pidx(p2)];
    const float q0r = 0.5f * (F1.x + F2.x), q0i = 0.5f * (F1.y - F2.y);
    const float q1r = 0.5f * (F1.y + F2.y), q1i = 0.5f * (F2.x - F1.x);
    const int  ix = (bin <= 512) ? bin : 1024 - bin;
    const float sg = (bin <= 512) ? 1.0f : -1.0f;
    float2 m0 = m0s[pidx16(ix)], m1 = m1s[pidx16(ix)];
    m0.y *= sg; m1.y *= sg;
    const float z0r = m0.x * q0r + m0.y * q0i, z0i = m0.y * q0r - m0.x * q0i;
    const float z1r = m1.x * q1r + m1.y * q1i, z1i = m1.y * q1r - m1.x * q1i;
    z[m] = make_float2(z0r - z1i, z0i + z1r);    // z0 + i*z1
  }
  __syncthreads();
  #pragma unroll
  for (int m = 0; m < 4; ++m) buf[pidx(t + 256 * m)] = z[m];
  __syncthreads();
  #pragma unroll
  for (int n = 0; n < 4; ++n) x[n] = buf[pidx(4 * t + n)];

  inv_stage<1>(x, t);   xchg<1, 4>(buf, x, t);
  inv_stage<4>(x, t);   xchg<4, 16>(buf, x, t);
  inv_stage<16>(x, t);  xchg<16, 64>(buf, x, t);
  inv_stage<64>(x, t);  xchg<64, 256>(buf, x, t);
  inv_stage<256>(x, t);

  const float sc = 1.0f / 1024.0f;
  #pragma unroll
  for (int n = 0; n < 4; ++n) {
    const int i = t + 256 * n;
    row0[i] = x[n].x * sc;
    row1[i] = x[n].y * sc;
  }
}

// ---------------------------------------------------------------------------
extern "C" void kernel_launch(void* const* d_in, const int* in_sizes, int n_in,
                              void* d_out, int out_size, void* d_ws, size_t ws_size,
                              hipStream_t stream) {
  (void)in_sizes; (void)n_in; (void)out_size;
  const float* x  = (const float*)d_in[0];
  const float* Wq = (const float*)d_in[1];
  const float* Wk = (const float*)d_in[2];
  const float* Wv = (const float*)d_in[3];
  float* out = (float*)d_out;

  // ws layout for MH rows/pass, nB batches/pass:
  //   Wb   : 3*1024*1024 bf16       = 6.29 MB
  //   xb   : MH*1024 bf16
  //   KV/P : MH rows * 4 KB
  //   csum : nB*64*512 float2
  // Single-pass (MH=8192): 57.67 MB; two-pass (MH=4096): 32.0 MB. Branch on
  // ws_size — constant across calls, so graph-safe.
  const size_t wbytes = (size_t)3 * DD * DD * 2;
  auto need = [&](size_t MHr, size_t nB) {
    return wbytes + MHr * DD * 2 + MHr * 4096 + nB * CH * 512 * 8;
  };
  const int nPass = (ws_size >= need(8192, 4)) ? 1 : 2;
  const size_t MH = MM / nPass;          // rows per pass
  const int    nB = BB / nPass;          // batches per pass

  char* ws = (char*)d_ws;
  unsigned short* Wb = (unsigned short*)ws;
  unsigned short* xb = (unsigned short*)(ws + wbytes);
  unsigned short* KV = (unsigned short*)(ws + wbytes + MH * DD * 2);
  float2*       csum = (float2*)((char*)KV + MH * 4096);

  convert_w<<<dim3(DD * DD / 1024, 3), 256, 0, stream>>>(Wq, Wk, Wv, Wb);

  for (int h = 0; h < nPass; ++h) {
    const float* xh   = x   + (size_t)h * MH * DD;
    float*       outh = out + (size_t)h * MH * DD;

    convert_bf16<<<MH * DD / 1024, 256, 0, stream>>>(xh, xb);
    gemm_mfma<<<dim3(MH / 256, DD / 256, 3), dim3(512), 0, stream>>>(xb, Wb, outh, KV);
    bind_kernel<<<MH, 256, 0, stream>>>(KV);
    scan_chunk_sum<<<dim3(CH, nB * 2), 256, 0, stream>>>((const float2*)KV, csum);
    scan_chunk_scan<<<nB * 2, 256, 0, stream>>>(csum);
    scan_apply<<<dim3(CH, nB * 2), 256, 0, stream>>>((float2*)KV, csum);
    unbind_kernel<<<MH / 2, 256, 0, stream>>>(outh, (const float2*)KV);
  }
}

// Round 6
// 225.900 us; speedup vs baseline: 1.0839x; 1.0123x over previous
//
#include <hip/hip_runtime.h>

// Problem constants: B=4, S=2048, D=1024
#define BB 4
#define SS 2048
#define DD 1024
#define MM 8192               // total rows
#define CH 64                 // scan chunks per batch
#define RR 32                 // rows per chunk (CH*RR = SS)
#define PI_F 3.14159265358979323846f

typedef __attribute__((ext_vector_type(8))) short bf16x8;
typedef __attribute__((ext_vector_type(4))) float f32x4;

// ---------------------------------------------------------------------------
// fp32 <-> bf16 helpers (RNE)
// ---------------------------------------------------------------------------
__device__ __forceinline__ unsigned short f2bf(float f) {
  unsigned int u = __float_as_uint(f);
  u = (u + 0x7FFFu + ((u >> 16) & 1u)) >> 16;
  return (unsigned short)u;
}
__device__ __forceinline__ float bf2f(unsigned short h) {
  return __uint_as_float(((unsigned int)h) << 16);
}

__global__ __launch_bounds__(256) void convert_bf16(
    const float* __restrict__ src, unsigned short* __restrict__ dst) {
  const long i = ((long)blockIdx.x * 256 + threadIdx.x) * 4;
  const float4 v = *(const float4*)&src[i];
  ushort4 o;
  o.x = f2bf(v.x); o.y = f2bf(v.y); o.z = f2bf(v.z); o.w = f2bf(v.w);
  *(ushort4*)&dst[i] = o;
}

__global__ __launch_bounds__(256) void convert_w(
    const float* __restrict__ Wq, const float* __restrict__ Wk,
    const float* __restrict__ Wv, unsigned short* __restrict__ dst) {
  const int z = blockIdx.y;
  const float* src = (z == 0) ? Wq : (z == 1) ? Wk : Wv;
  const long i = ((long)blockIdx.x * 256 + threadIdx.x) * 4;
  const float4 v = *(const float4*)&src[i];
  ushort4 o;
  o.x = f2bf(v.x); o.y = f2bf(v.y); o.z = f2bf(v.z); o.w = f2bf(v.w);
  *(ushort4*)&dst[(size_t)z * DD * DD + i] = o;
}

// ---------------------------------------------------------------------------
// MFMA GEMM — 128x128 tile, BK=64, 4 waves (2M x 2N, 64x64 out/wave),
// R5's proven 2-phase counted-vmcnt schedule, now at 2 blocks/CU (LDS 64 KB)
// so a co-resident block fills each barrier/drain window (m114 mechanism).
//   Ph0(T): reads A(T) all (8) + B(T) nt0,nt1 (4); stages B(T+1) u0-3;
//           MMA(nt0), MMA(nt1).
//   Ph1(T): reads B(T) nt2,nt3 (4); stages A(T+2) u0-3; MMA(nt2), MMA(nt3).
// vmcnt(4) once per tile at Ph0: queue there = [.., B(T)x4 (Ph0(T-1)),
// A(T+1)x4 (Ph1(T-1))] -> GW(4) leaves A(T+1) in flight, B(T) landed.
// GW(0) at final tile. Region-reuse safety (>=1 barrier, reads lgkm-retired
// pre-barrier since their MMAs precede it):
//   Ph0(T) STB B(T+1) [buf^1]: B(T-1) last read Ph1(T-1) -> 1 barrier
//   Ph1(T) STA A(T+2) [buf]  : A(T)   last read Ph0(T)   -> 1 barrier
// Unit = 256 thr x 16 B = 4 KB = 32 rows x 64 cols. XOR-quad swizzle
// identical to the 0-conflict baseline (stage g = kq^(row&7), read
// (kh*4+kq)^(fr&7)).
// z=0: q fp32 -> outq. z=1,2: k,v bf16 -> KV interleaved [row][k|v], ld 2048.
// ---------------------------------------------------------------------------
__device__ __forceinline__ void async16(const void* g, void* l) {
  __builtin_amdgcn_global_load_lds(
      (const __attribute__((address_space(1))) void*)g,
      (__attribute__((address_space(3))) void*)l, 16, 0, 0);
}

#define GW(n)  asm volatile("s_waitcnt vmcnt(" #n ")" ::: "memory")
#define BAR()  asm volatile("s_barrier" ::: "memory")
#define SB0()  __builtin_amdgcn_sched_barrier(0)

#define STA(buf, i, T) async16(xb + (size_t)(m0 + 32 * (i)) * DD + (T) * 64 + sOff, \
                               &Als[(buf) * 8192 + (i) * 2048 + slot8])
#define STB(buf, i, T) async16(W + (size_t)(n0 + 32 * (i)) * DD + (T) * 64 + sOff, \
                               &Bls[(buf) * 8192 + (i) * 2048 + slot8])
#define LDA(buf) { _Pragma("unroll") for (int mt = 0; mt < 4; ++mt) { \
    af[mt][0] = *(const bf16x8*)&Als[(buf) * 8192 + aRd + mt * 1024 + qoff0]; \
    af[mt][1] = *(const bf16x8*)&Als[(buf) * 8192 + aRd + mt * 1024 + qoff1]; } }
#define LDB(buf, nt, bank) { \
    bank[0] = *(const bf16x8*)&Bls[(buf) * 8192 + bRd + (nt) * 1024 + qoff0]; \
    bank[1] = *(const bf16x8*)&Bls[(buf) * 8192 + bRd + (nt) * 1024 + qoff1]; }
#define MMA(nt, bank) { __builtin_amdgcn_s_setprio(1); \
    _Pragma("unroll") for (int mt = 0; mt < 4; ++mt) { \
      acc[mt][nt] = __builtin_amdgcn_mfma_f32_16x16x32_bf16(af[mt][0], bank[0], acc[mt][nt], 0, 0, 0); \
      acc[mt][nt] = __builtin_amdgcn_mfma_f32_16x16x32_bf16(af[mt][1], bank[1], acc[mt][nt], 0, 0, 0); } \
    __builtin_amdgcn_s_setprio(0); }

__global__ __launch_bounds__(256, 2) void gemm_mfma(
    const unsigned short* __restrict__ xb,
    const unsigned short* __restrict__ Wb,
    float* __restrict__ outq, unsigned short* __restrict__ KV) {
  const int z = blockIdx.z;
  const unsigned short* W = Wb + (size_t)z * DD * DD;

  __shared__ unsigned short Als[2 * 8192];   // 32 KB
  __shared__ unsigned short Bls[2 * 8192];   // 32 KB

  const int tid  = threadIdx.x;
  const int lane = tid & 63;
  const int w    = tid >> 6;          // wave 0..3
  const int wm   = w >> 1;            // M half (0..1)
  const int wn   = w & 1;             // N half (0..1)
  const int fr   = lane & 15;
  const int kq   = lane >> 4;

  const int m0 = blockIdx.x * 128;
  const int n0 = blockIdx.y * 128;

  // staging geometry: unit = 4 KB = 256 threads x 16 B; 32 rows x 64 cols
  const int srow  = tid >> 3;                  // row within 32-row unit
  const int sq    = (tid & 7) ^ (srow & 7);    // swizzled source quad
  const int slot8 = tid * 8;                   // shorts (lane-linear dest)
  const size_t sOff = (size_t)srow * DD + sq * 8;

  // read-side addressing (same XOR as stage-source swizzle)
  const int qoff0 = ((0 + kq) ^ (fr & 7)) * 8;
  const int qoff1 = ((4 + kq) ^ (fr & 7)) * 8;
  const int aRd = wm * 4096 + fr * 64;
  const int bRd = wn * 4096 + fr * 64;

  f32x4 acc[4][4] = {};
  bf16x8 af[4][2];
  bf16x8 bva[2], bvb[2];

  // Prologue: A(0)x4, B(0)x4, A(1)x4 — order defines the vmcnt queue.
  STA(0, 0, 0); STA(0, 1, 0); STA(0, 2, 0); STA(0, 3, 0);
  STB(0, 0, 0); STB(0, 1, 0); STB(0, 2, 0); STB(0, 3, 0);
  STA(1, 0, 1); STA(1, 1, 1); STA(1, 2, 1); STA(1, 3, 1);

  // Main loop: tiles 0..13 (NT=16), 2 phases/tile, vmcnt(4) once per tile.
  for (int T = 0; T < 14; ++T) {
    const int buf = T & 1;
    // Ph0
    SB0(); GW(4); BAR();
    LDB(buf, 0, bva);
    LDA(buf);
    LDB(buf, 1, bvb);
    STB(buf ^ 1, 0, T + 1); STB(buf ^ 1, 1, T + 1);
    STB(buf ^ 1, 2, T + 1); STB(buf ^ 1, 3, T + 1);
    MMA(0, bva);
    MMA(1, bvb);
    // Ph1
    SB0(); BAR();
    LDB(buf, 2, bva);
    LDB(buf, 3, bvb);
    STA(buf, 0, T + 2); STA(buf, 1, T + 2);
    STA(buf, 2, T + 2); STA(buf, 3, T + 2);
    MMA(2, bva);
    MMA(3, bvb);
  }
  // T = 14 (buf 0): Ph0 stages B(15); Ph1 stages nothing.
  SB0(); GW(4); BAR();
  LDB(0, 0, bva); LDA(0); LDB(0, 1, bvb);
  STB(1, 0, 15); STB(1, 1, 15); STB(1, 2, 15); STB(1, 3, 15);
  MMA(0, bva); MMA(1, bvb);
  SB0(); BAR();
  LDB(0, 2, bva); LDB(0, 3, bvb);
  MMA(2, bva); MMA(3, bvb);
  // T = 15 (buf 1): drain all outstanding stages, no new stages.
  SB0(); GW(0); BAR();
  LDB(1, 0, bva); LDA(1); LDB(1, 1, bvb);
  MMA(0, bva); MMA(1, bvb);
  SB0(); BAR();
  LDB(1, 2, bva); LDB(1, 3, bvb);
  MMA(2, bva); MMA(3, bvb);

  // Epilogue
  const int col = lane & 15;
  const int r0  = (lane >> 4) * 4;
  const int mBase = m0 + wm * 64;
  const int nBase = n0 + wn * 64;
  if (z == 0) {
    #pragma unroll
    for (int mt = 0; mt < 4; ++mt)
      #pragma unroll
      for (int nt = 0; nt < 4; ++nt)
        #pragma unroll
        for (int r = 0; r < 4; ++r)
          outq[(size_t)(mBase + mt * 16 + r0 + r) * DD + nBase + nt * 16 + col] =
              acc[mt][nt][r];
  } else {
    unsigned short* Ck = KV + (size_t)(z - 1) * DD;
    #pragma unroll
    for (int mt = 0; mt < 4; ++mt)
      #pragma unroll
      for (int nt = 0; nt < 4; ++nt)
        #pragma unroll
        for (int r = 0; r < 4; ++r)
          Ck[(size_t)(mBase + mt * 16 + r0 + r) * 2048 + nBase + nt * 16 + col] =
              f2bf(acc[mt][nt][r]);
  }
}

// ---------------------------------------------------------------------------
// Radix-4 FFT, N=1024, 256 threads, 4 complex/thread in registers (proven
// sincos version). Forward DIF -> base-4 digit-reversed order; inverse DIT.
// ---------------------------------------------------------------------------
__device__ __forceinline__ int pidx(int i) { return i + (i >> 6); }
#define BUFSZ 1040
__device__ __forceinline__ int pidx16(int i) { return i + (i >> 4); }
#define MEMSZ 546   // 513 slots + pads

__device__ __forceinline__ int rev4(int p) {
  unsigned r = __brev((unsigned)p) >> 22;
  return (int)(((r & 0x155u) << 1) | ((r & 0x2AAu) >> 1));
}

__host__ __device__ constexpr int clog2(int s) {
  return (s == 256) ? 8 : (s == 64) ? 6 : (s == 16) ? 4 : (s == 4) ? 2 : 0;
}

template <int S>
__device__ __forceinline__ void fwd_stage(float2 x[4], int t) {
  float c1 = 1.0f, s1 = 0.0f;
  if (S > 1) {
    const int j = t & (S - 1);
    __sincosf(-2.0f * PI_F * (float)j / (float)(4 * S), &s1, &c1);
  }
  const float c2 = c1 * c1 - s1 * s1, s2 = 2.0f * c1 * s1;
  const float c3 = c1 * c2 - s1 * s2, s3 = c1 * s2 + s1 * c2;
  const float Ar = x[0].x + x[2].x, Ai = x[0].y + x[2].y;
  const float Br = x[1].x + x[3].x, Bi = x[1].y + x[3].y;
  const float Cr = x[0].x - x[2].x, Ci = x[0].y - x[2].y;
  const float dr = x[1].x - x[3].x, di = x[1].y - x[3].y;
  const float y1r = Cr + di, y1i = Ci - dr;
  const float y2r = Ar - Br, y2i = Ai - Bi;
  const float y3r = Cr - di, y3i = Ci + dr;
  x[0] = make_float2(Ar + Br, Ai + Bi);
  x[1] = make_float2(y1r * c1 - y1i * s1, y1r * s1 + y1i * c1);
  x[2] = make_float2(y2r * c2 - y2i * s2, y2r * s2 + y2i * c2);
  x[3] = make_float2(y3r * c3 - y3i * s3, y3r * s3 + y3i * c3);
}

template <int S>
__device__ __forceinline__ void inv_stage(float2 x[4], int t) {
  float c1 = 1.0f, s1 = 0.0f;
  if (S > 1) {
    const int j = t & (S - 1);
    __sincosf(2.0f * PI_F * (float)j / (float)(4 * S), &s1, &c1);
  }
  const float c2 = c1 * c1 - s1 * s1, s2 = 2.0f * c1 * s1;
  const float c3 = c1 * c2 - s1 * s2, s3 = c1 * s2 + s1 * c2;
  const float u0r = x[0].x,                   u0i = x[0].y;
  const float u1r = x[1].x * c1 - x[1].y * s1, u1i = x[1].x * s1 + x[1].y * c1;
  const float u2r = x[2].x * c2 - x[2].y * s2, u2i = x[2].x * s2 + x[2].y * c2;
  const float u3r = x[3].x * c3 - x[3].y * s3, u3i = x[3].x * s3 + x[3].y * c3;
  const float Er = u0r + u2r, Ei = u0i + u2i;
  const float Fr = u0r - u2r, Fi = u0i - u2i;
  const float Gr = u1r + u3r, Gi = u1i + u3i;
  const float Hr = u1r - u3r, Hi = u1i - u3i;
  x[0] = make_float2(Er + Gr, Ei + Gi);
  x[1] = make_float2(Fr - Hi, Fi + Hr);
  x[2] = make_float2(Er - Gr, Ei - Gi);
  x[3] = make_float2(Fr + Hi, Fi - Hr);
}

template <int SW, int SR>
__device__ __forceinline__ void xchg(float2* buf, float2 x[4], int t) {
  constexpr int LW2 = clog2(SW), LR = clog2(SR);
  #pragma unroll
  for (int n = 0; n < 4; ++n)
    buf[pidx(((t >> LW2) << (LW2 + 2)) + (t & (SW - 1)) + n * SW)] = x[n];
  __syncthreads();
  #pragma unroll
  for (int n = 0; n < 4; ++n)
    x[n] = buf[pidx(((t >> LR) << (LR + 2)) + (t & (SR - 1)) + n * SR)];
  __syncthreads();
}

__device__ __forceinline__ void fwd_fft(float2* buf, float2 x[4], int t) {
  fwd_stage<256>(x, t); xchg<256, 64>(buf, x, t);
  fwd_stage<64>(x, t);  xchg<64, 16>(buf, x, t);
  fwd_stage<16>(x, t);  xchg<16, 4>(buf, x, t);
  fwd_stage<4>(x, t);   xchg<4, 1>(buf, x, t);
  fwd_stage<1>(x, t);
  #pragma unroll
  for (int n = 0; n < 4; ++n) buf[pidx(4 * t + n)] = x[n];
  __syncthreads();
}

// ---------------------------------------------------------------------------
// Bind (in place): KV row [k|v] bf16 (4 KB) -> one FFT of k+iv, Hermitian
// split, P = fk*fv packed to HALF spectrum over the same 4 KB:
//   slot 0 = (P[0], P[512]) (both exactly real), slot s = P[s], s=1..511.
// ---------------------------------------------------------------------------
__global__ __launch_bounds__(256) void bind_kernel(unsigned short* __restrict__ KV) {
  __shared__ float2 buf[BUFSZ];
  const int t = threadIdx.x;
  unsigned short* row = KV + (long)blockIdx.x * 2048;

  float2 x[4];
  #pragma unroll
  for (int n = 0; n < 4; ++n) {
    const int i = t + 256 * n;
    x[n] = make_float2(bf2f(row[i]), bf2f(row[1024 + i]));   // k + i*v
  }
  fwd_fft(buf, x, t);

  float2* Prow = (float2*)row;
  #pragma unroll
  for (int m = 0; m < 2; ++m) {
    const int s = t + 256 * m;
    if (s == 0) {
      const float2 W0   = buf[pidx(0)];
      const float2 W512 = buf[pidx(2)];
      Prow[0] = make_float2(W0.x * W0.y, W512.x * W512.y);
    } else {
      const int p1 = rev4(s);
      const int p2 = rev4(1024 - s);
      const float2 F1 = buf[pidx(p1)], F2 = buf[pidx(p2)];
      const float fkr = 0.5f * (F1.x + F2.x), fki = 0.5f * (F1.y - F2.y);
      const float fvr = 0.5f * (F1.y + F2.y), fvi = 0.5f * (F2.x - F1.x);
      Prow[s] = make_float2(fkr * fvr - fki * fvi, fkr * fvi + fki * fvr);
    }
  }
}

// ---------------------------------------------------------------------------
// Causal cumsum over s per packed bin; grids cover nB batches (gridDim.y=2*nB).
// Loads batched 8-deep (breaks dependent-latency chain); order preserved.
// ---------------------------------------------------------------------------
__global__ __launch_bounds__(256) void scan_chunk_sum(
    const float2* __restrict__ P, float2* __restrict__ csum) {
  const int chunk = blockIdx.x;
  const int batch = blockIdx.y >> 1;
  const int f = (blockIdx.y & 1) * 256 + threadIdx.x;
  long base = ((long)batch * SS + (long)chunk * RR) * 512 + f;
  float sr = 0.0f, si = 0.0f;
  #pragma unroll
  for (int i0 = 0; i0 < RR; i0 += 8) {
    float2 p[8];
    #pragma unroll
    for (int j = 0; j < 8; ++j) p[j] = P[base + (long)(i0 + j) * 512];
    #pragma unroll
    for (int j = 0; j < 8; ++j) { sr += p[j].x; si += p[j].y; }
  }
  csum[((long)batch * CH + chunk) * 512 + f] = make_float2(sr, si);
}

__global__ __launch_bounds__(256) void scan_chunk_scan(float2* csum) {
  const int idx = blockIdx.x * 256 + threadIdx.x;
  const int batch = idx >> 9;
  const int f = idx & 511;
  float2 v[CH];
  #pragma unroll
  for (int c = 0; c < CH; ++c) v[c] = csum[((long)batch * CH + c) * 512 + f];
  float rr = 0.0f, ri = 0.0f;
  #pragma unroll
  for (int c = 0; c < CH; ++c) {
    const float2 x = v[c];
    csum[((long)batch * CH + c) * 512 + f] = make_float2(rr, ri);
    rr += x.x; ri += x.y;
  }
}

__global__ __launch_bounds__(256) void scan_apply(
    float2* __restrict__ P, const float2* __restrict__ csum) {
  const int chunk = blockIdx.x;
  const int batch = blockIdx.y >> 1;
  const int f = (blockIdx.y & 1) * 256 + threadIdx.x;
  float2 off = csum[((long)batch * CH + chunk) * 512 + f];
  float ar = off.x, ai = off.y;
  long base = ((long)batch * SS + (long)chunk * RR) * 512 + f;
  #pragma unroll
  for (int i0 = 0; i0 < RR; i0 += 8) {
    float2 p[8];
    #pragma unroll
    for (int j = 0; j < 8; ++j) p[j] = P[base + (long)(i0 + j) * 512];
    #pragma unroll
    for (int j = 0; j < 8; ++j) {
      ar += p[j].x; ai += p[j].y;
      P[base + (long)(i0 + j) * 512] = make_float2(ar, ai);
    }
  }
}

// ---------------------------------------------------------------------------
// Unbind, 2 rows/block (in place on d_out). mem rows Hermitian-packed;
// unpack into LDS, gather with predicated conj; one fwd FFT (q0+iq1),
// one inv FFT (z0+iz1).
// ---------------------------------------------------------------------------
__global__ __launch_bounds__(256) void unbind_kernel(
    float* __restrict__ qout, const float2* __restrict__ mem) {
  __shared__ float2 buf[BUFSZ];
  __shared__ float2 m0s[MEMSZ], m1s[MEMSZ];
  const int t = threadIdx.x;
  const long r0 = (long)blockIdx.x * 2;
  float* row0 = qout + r0 * DD;
  float* row1 = row0 + DD;
  const float2* mem0 = mem + r0 * 512;
  const float2* mem1 = mem0 + 512;

  float2 x[4];
  #pragma unroll
  for (int n = 0; n < 4; ++n) {
    const int i = t + 256 * n;
    x[n] = make_float2(row0[i], row1[i]);        // q0 + i*q1
  }
  #pragma unroll
  for (int n = 0; n < 2; ++n) {
    const int s = t + 256 * n;
    const float2 a = mem0[s], b = mem1[s];
    if (s == 0) {
      m0s[pidx16(0)]   = make_float2(a.x, 0.0f);
      m0s[pidx16(512)] = make_float2(a.y, 0.0f);
      m1s[pidx16(0)]   = make_float2(b.x, 0.0f);
      m1s[pidx16(512)] = make_float2(b.y, 0.0f);
    } else {
      m0s[pidx16(s)] = a;
      m1s[pidx16(s)] = b;
    }
  }
  fwd_fft(buf, x, t);   // internal barriers order the m*s writes too

  float2 z[4];
  #pragma unroll
  for (int m = 0; m < 4; ++m) {
    const int p   = t + 256 * m;
    const int bin = rev4(p);
    const int p2  = rev4((1024 - bin) & 1023);
    const float2 F1 = buf[pidx(p)], F2 = buf[pidx(p2)];
    const float q0r = 0.5f * (F1.x + F2.x), q0i = 0.5f * (F1.y - F2.y);
    const float q1r = 0.5f * (F1.y + F2.y), q1i = 0.5f * (F2.x - F1.x);
    const int  ix = (bin <= 512) ? bin : 1024 - bin;
    const float sg = (bin <= 512) ? 1.0f : -1.0f;
    float2 m0 = m0s[pidx16(ix)], m1 = m1s[pidx16(ix)];
    m0.y *= sg; m1.y *= sg;
    const float z0r = m0.x * q0r + m0.y * q0i, z0i = m0.y * q0r - m0.x * q0i;
    const float z1r = m1.x * q1r + m1.y * q1i, z1i = m1.y * q1r - m1.x * q1i;
    z[m] = make_float2(z0r - z1i, z0i + z1r);    // z0 + i*z1
  }
  __syncthreads();
  #pragma unroll
  for (int m = 0; m < 4; ++m) buf[pidx(t + 256 * m)] = z[m];
  __syncthreads();
  #pragma unroll
  for (int n = 0; n < 4; ++n) x[n] = buf[pidx(4 * t + n)];

  inv_stage<1>(x, t);   xchg<1, 4>(buf, x, t);
  inv_stage<4>(x, t);   xchg<4, 16>(buf, x, t);
  inv_stage<16>(x, t);  xchg<16, 64>(buf, x, t);
  inv_stage<64>(x, t);  xchg<64, 256>(buf, x, t);
  inv_stage<256>(x, t);

  const float sc = 1.0f / 1024.0f;
  #pragma unroll
  for (int n = 0; n < 4; ++n) {
    const int i = t + 256 * n;
    row0[i] = x[n].x * sc;
    row1[i] = x[n].y * sc;
  }
}

// ---------------------------------------------------------------------------
extern "C" void kernel_launch(void* const* d_in, const int* in_sizes, int n_in,
                              void* d_out, int out_size, void* d_ws, size_t ws_size,
                              hipStream_t stream) {
  (void)in_sizes; (void)n_in; (void)out_size;
  const float* x  = (const float*)d_in[0];
  const float* Wq = (const float*)d_in[1];
  const float* Wk = (const float*)d_in[2];
  const float* Wv = (const float*)d_in[3];
  float* out = (float*)d_out;

  // ws layout for MH rows/pass, nB batches/pass:
  //   Wb   : 3*1024*1024 bf16       = 6.29 MB
  //   xb   : MH*1024 bf16
  //   KV/P : MH rows * 4 KB
  //   csum : nB*64*512 float2
  // Single-pass (MH=8192): 57.67 MB; two-pass (MH=4096): 32.0 MB. Branch on
  // ws_size — constant across calls, so graph-safe.
  const size_t wbytes = (size_t)3 * DD * DD * 2;
  auto need = [&](size_t MHr, size_t nB) {
    return wbytes + MHr * DD * 2 + MHr * 4096 + nB * CH * 512 * 8;
  };
  const int nPass = (ws_size >= need(8192, 4)) ? 1 : 2;
  const size_t MH = MM / nPass;          // rows per pass
  const int    nB = BB / nPass;          // batches per pass

  char* ws = (char*)d_ws;
  unsigned short* Wb = (unsigned short*)ws;
  unsigned short* xb = (unsigned short*)(ws + wbytes);
  unsigned short* KV = (unsigned short*)(ws + wbytes + MH * DD * 2);
  float2*       csum = (float2*)((char*)KV + MH * 4096);

  convert_w<<<dim3(DD * DD / 1024, 3), 256, 0, stream>>>(Wq, Wk, Wv, Wb);

  for (int h = 0; h < nPass; ++h) {
    const float* xh   = x   + (size_t)h * MH * DD;
    float*       outh = out + (size_t)h * MH * DD;

    convert_bf16<<<MH * DD / 1024, 256, 0, stream>>>(xh, xb);
    gemm_mfma<<<dim3(MH / 128, DD / 128, 3), dim3(256), 0, stream>>>(xb, Wb, outh, KV);
    bind_kernel<<<MH, 256, 0, stream>>>(KV);
    scan_chunk_sum<<<dim3(CH, nB * 2), 256, 0, stream>>>((const float2*)KV, csum);
    scan_chunk_scan<<<nB * 2, 256, 0, stream>>>(csum);
    scan_apply<<<dim3(CH, nB * 2), 256, 0, stream>>>((float2*)KV, csum);
    unbind_kernel<<<MH / 2, 256, 0, stream>>>(outh, (const float2*)KV);
  }
}